// Round 10
// baseline (241.662 us; speedup 1.0000x reference)
//
#include <hip/hip_runtime.h>
#include <math.h>
#include <stdint.h>

#define ALPHA 0.2f
#define BW_CHUNK 8192             // edges per hist block (16 x 512)
#define BW2_CHUNK 4096            // edges per binwrite block (16 x 256)
#define BUCKET_SHIFT 8            // 256 nodes per bucket
#define PHC_CAP 12288             // bucket LDS capacity (entries); mean ~8192, +45 sigma

typedef __attribute__((ext_vector_type(8))) short bf16x8;
typedef __attribute__((ext_vector_type(4))) float f32x4;
typedef __attribute__((ext_vector_type(8))) unsigned short u16x8;

// bf16 round-to-nearest-even
__device__ __forceinline__ unsigned short f2bf(float f)
{
    unsigned int u = __float_as_uint(f);
    unsigned int r = (u + 0x7FFFu + ((u >> 16) & 1u)) >> 16;
    return (unsigned short)r;
}

// ---------------------------------------------------------------------------
// MFMA GEMM: h = x @ W  [N,256]x[256,64] -> hb (bf16), f1/f2 from the fp32
// accumulators. 512 threads = 8 waves; tile 128 rows x 64 cols; BK=64.
// ---------------------------------------------------------------------------
#define GEMM_BM 128

__global__ __launch_bounds__(512) void gat_gemm(
    const float* __restrict__ x, const float* __restrict__ W,
    const float* __restrict__ a1, const float* __restrict__ a1b,
    const float* __restrict__ a2, const float* __restrict__ a2b,
    unsigned short* __restrict__ hb, float* __restrict__ f1, float* __restrict__ f2,
    int N)
{
    __shared__ unsigned short wt[64 * 256];   // 32 KB: wt[col][k] (swizzled)
    __shared__ unsigned short xs[128 * 64];   // 16 KB: xs[row][k-in-chunk] (swizzled)

    const int tid  = threadIdx.x;
    const int lane = tid & 63;
    const int w    = tid >> 6;                  // wave 0..7
    const int cg   = lane & 15;                 // col-in-tile / row-in-tile
    const int g    = lane >> 4;                 // quad group 0..3
    const long long row0 = (long long)blockIdx.x * GEMM_BM;

    // ---- stage W transposed (once): thread -> col c = tid>>3, k0 = (tid&7)*32
    {
        const int c  = tid >> 3;
        const int k0 = (tid & 7) * 32;
        unsigned short tmp[32];
#pragma unroll
        for (int j = 0; j < 32; ++j)
            tmp[j] = f2bf(W[(k0 + j) * 64 + c]);
        const int xorv = (c & 7) << 4;
        char* wb = (char*)wt + c * 512;
#pragma unroll
        for (int q = 0; q < 4; ++q) {
            int kbyte = (k0 + q * 8) * 2;
            *(u16x8*)(wb + (kbyte ^ xorv)) = *(u16x8*)&tmp[q * 8];
        }
    }

    f32x4 acc[4];
#pragma unroll
    for (int ct = 0; ct < 4; ++ct) acc[ct] = (f32x4){0.f, 0.f, 0.f, 0.f};

    // A-frag LDS address (constant across chunks)
    const int arow  = w * 16 + cg;
    const int axor  = (arow & 7) << 4;
    char* const abase = (char*)xs + arow * 128;

    for (int kc = 0; kc < 256; kc += 64) {
        __syncthreads();   // previous chunk's reads done (and W writes on iter 0)
        // ---- stage x chunk: 128 rows x 64 k; thread -> row tid>>2, kseg (tid&3)*16
        {
            const int r  = tid >> 2;
            const int ks = (tid & 3) * 16;
            long long gr = row0 + r;
            if (gr > (long long)N - 1) gr = (long long)N - 1;
            const float* xp = &x[gr * 256 + kc + ks];
            float4 v0 = *(const float4*)&xp[0];
            float4 v1 = *(const float4*)&xp[4];
            float4 v2 = *(const float4*)&xp[8];
            float4 v3 = *(const float4*)&xp[12];
            unsigned short tmp[16];
            tmp[0]=f2bf(v0.x); tmp[1]=f2bf(v0.y); tmp[2]=f2bf(v0.z); tmp[3]=f2bf(v0.w);
            tmp[4]=f2bf(v1.x); tmp[5]=f2bf(v1.y); tmp[6]=f2bf(v1.z); tmp[7]=f2bf(v1.w);
            tmp[8]=f2bf(v2.x); tmp[9]=f2bf(v2.y); tmp[10]=f2bf(v2.z); tmp[11]=f2bf(v2.w);
            tmp[12]=f2bf(v3.x); tmp[13]=f2bf(v3.y); tmp[14]=f2bf(v3.z); tmp[15]=f2bf(v3.w);
            const int xorv = (r & 7) << 4;
            char* xb = (char*)xs + r * 128;
            *(u16x8*)(xb + ((ks * 2) ^ xorv))      = *(u16x8*)&tmp[0];
            *(u16x8*)(xb + ((ks * 2 + 16) ^ xorv)) = *(u16x8*)&tmp[8];
        }
        __syncthreads();

#pragma unroll
        for (int s = 0; s < 2; ++s) {
            bf16x8 af = *(bf16x8*)(abase + (((s * 32 + g * 8) * 2) ^ axor));
#pragma unroll
            for (int ct = 0; ct < 4; ++ct) {
                const int col = ct * 16 + cg;
                const int kbyte = (kc + s * 32) * 2 + g * 16;
                bf16x8 bf_ = *(bf16x8*)((char*)wt + col * 512 + (kbyte ^ ((col & 7) << 4)));
                acc[ct] = __builtin_amdgcn_mfma_f32_16x16x32_bf16(af, bf_, acc[ct], 0, 0, 0);
            }
        }
    }

    // ---- epilogue: store bf16 h; f1/f2 from fp32 accumulators
    float a1v[4], a2v[4];
#pragma unroll
    for (int ct = 0; ct < 4; ++ct) {
        a1v[ct] = a1[ct * 16 + cg];
        a2v[ct] = a2[ct * 16 + cg];
    }
    const float b1 = a1b[0], b2 = a2b[0];

#pragma unroll
    for (int r = 0; r < 4; ++r) {
        const long long row = row0 + w * 16 + g * 4 + r;
        const bool ok = (row < N);
        float p1 = 0.f, p2 = 0.f;
#pragma unroll
        for (int ct = 0; ct < 4; ++ct) {
            float hv = acc[ct][r];
            if (ok) hb[row * 64 + ct * 16 + cg] = f2bf(hv);
            p1 = fmaf(hv, a1v[ct], p1);
            p2 = fmaf(hv, a2v[ct], p2);
        }
#pragma unroll
        for (int d = 8; d > 0; d >>= 1) {
            p1 += __shfl_xor(p1, d);
            p2 += __shfl_xor(p2, d);
        }
        if (ok && cg == 0) {
            f1[row] = p1 + b1;
            f2[row] = p2 + b2;
        }
    }
}

// ---------------------------------------------------------------------------
// Phase A: per-block LDS bucket histogram -> ONE global atomicAdd per bucket.
// ---------------------------------------------------------------------------
__global__ __launch_bounds__(512) void gat_hist(
    const int* __restrict__ src, int* __restrict__ bcnt, int E, int nbuck)
{
    __shared__ int hist[512];
    const int tid = threadIdx.x;
    hist[tid] = 0;
    __syncthreads();
    const long long base = (long long)blockIdx.x * BW_CHUNK;
#pragma unroll 4
    for (int k = 0; k < BW_CHUNK / 512; ++k) {
        long long i = base + k * 512 + tid;
        if (i < E) atomicAdd(&hist[src[i] >> BUCKET_SHIFT], 1);
    }
    __syncthreads();
    if (tid < nbuck && hist[tid]) atomicAdd(&bcnt[tid], hist[tid]);
}

// ---------------------------------------------------------------------------
// Single-block exclusive scan of bucket totals -> bbase[0..nbuck], cursor[].
// ---------------------------------------------------------------------------
__global__ __launch_bounds__(512) void gat_bscan(
    const int* __restrict__ bcnt, int* __restrict__ bbase,
    int* __restrict__ cursor, int nbuck, int E)
{
    __shared__ int s[512];
    const int t = threadIdx.x;
    int v = (t < nbuck) ? bcnt[t] : 0;
    s[t] = v;
    __syncthreads();
    for (int off = 1; off < 512; off <<= 1) {
        int u = (t >= off) ? s[t - off] : 0;
        __syncthreads();
        s[t] += u;
        __syncthreads();
    }
    if (t < nbuck) {
        int ex = s[t] - v;
        bbase[t]  = ex;
        cursor[t] = ex;
    }
    if (t == 0) bbase[nbuck] = E;
}

// ---------------------------------------------------------------------------
// Phase B (two-pass, NO register staging -> no scratch spill):
// pass 1: LDS bucket hist (src only; L3-resident re-read is cheap)
//         -> reserve contiguous per-bucket ranges (one global atomic each)
// pass 2: re-read edges, compute leaky logit, scatter via LDS cursors.
// Payload: {(dst<<8)|src_local, leaky_logit}.
// ---------------------------------------------------------------------------
__global__ __launch_bounds__(256) void gat_binwrite(
    const int* __restrict__ src, const int* __restrict__ dst,
    const float* __restrict__ adj,
    const float* __restrict__ f1, const float* __restrict__ f2,
    int* __restrict__ cursor, int2* __restrict__ bin, int E, int nbuck)
{
    __shared__ int hist[512];
    __shared__ int curs[512];
    const int tid = threadIdx.x;
    hist[tid] = 0;
    hist[tid + 256] = 0;
    __syncthreads();

    const long long base = (long long)blockIdx.x * BW2_CHUNK;
#pragma unroll 4
    for (int k = 0; k < BW2_CHUNK / 256; ++k) {
        long long i = base + k * 256 + tid;
        if (i < E) atomicAdd(&hist[src[i] >> BUCKET_SHIFT], 1);
    }
    __syncthreads();
    for (int b = tid; b < nbuck; b += 256) {
        int c = hist[b];
        curs[b] = c ? atomicAdd(&cursor[b], c) : 0;
    }
    __syncthreads();
#pragma unroll 2
    for (int k = 0; k < BW2_CHUNK / 256; ++k) {
        long long i = base + k * 256 + tid;
        if (i < E) {
            int s = src[i], d = dst[i];
            float a = adj[i];
            float e = a * f1[s] + a * f2[d];
            e = (e > 0.f) ? e : ALPHA * e;
            int r = atomicAdd(&curs[s >> BUCKET_SHIFT], 1);
            bin[r] = make_int2((d << BUCKET_SHIFT) | (s & 255), __float_as_int(e));
        }
    }
}

// ---------------------------------------------------------------------------
// Phase C: one block per bucket. Local degree hist + scan writes row_start;
// then in-place scatter {dst, p=exp(e)} into CSR order.
// ---------------------------------------------------------------------------
__global__ __launch_bounds__(512) void gat_bucket_scatter(
    const int* __restrict__ bbase, int* __restrict__ row_start,
    int2* __restrict__ csr, int N, int E)
{
    __shared__ int2 buf[PHC_CAP];
    __shared__ int hist[256];     // degree hist, later reused as cursors
    __shared__ int sc[256];       // inclusive scan
    const int tid = threadIdx.x;
    const int b = blockIdx.x;
    const int n0 = b << BUCKET_SHIFT;
    int n1 = n0 + 256; if (n1 > N) n1 = N;
    const int nn = n1 - n0;

    const int bstart = bbase[b];
    const int bend   = bbase[b + 1];
    int cntb = bend - bstart;
    if (cntb > PHC_CAP) cntb = PHC_CAP;           // statistically unreachable guard

    if (tid < 256) hist[tid] = 0;
    for (int i = tid; i < cntb; i += 512) buf[i] = csr[bstart + i];
    __syncthreads();

    for (int i = tid; i < cntb; i += 512)
        atomicAdd(&hist[buf[i].x & 255], 1);
    __syncthreads();

    int v = (tid < 256) ? hist[tid] : 0;
    if (tid < 256) sc[tid] = v;
    __syncthreads();
    for (int off = 1; off < 256; off <<= 1) {
        int u = (tid < 256 && tid >= off) ? sc[tid - off] : 0;
        __syncthreads();
        if (tid < 256) sc[tid] += u;
        __syncthreads();
    }
    if (tid < 256) {
        int ex = bstart + sc[tid] - v;   // exclusive prefix + bucket base
        hist[tid] = ex;                  // reuse as cursor
        if (tid < nn) row_start[n0 + tid] = ex;
    }
    if (b == gridDim.x - 1 && tid == 0) row_start[N] = E;
    __syncthreads();

    for (int i = tid; i < cntb; i += 512) {
        int2 e = buf[i];
        int sl = e.x & 255;
        int dv = e.x >> BUCKET_SHIFT;
        float p = __expf(__int_as_float(e.y));
        int pos = atomicAdd(&hist[sl], 1);
        csr[pos] = make_int2(dv, __float_as_int(p));
    }
}

// ---------------------------------------------------------------------------
// Fallback kernels + generic scan (only used if bucket limits are exceeded).
// ---------------------------------------------------------------------------
__global__ void gat_deg(const int* __restrict__ src, int* __restrict__ deg, int E)
{
    int i = blockIdx.x * blockDim.x + threadIdx.x;
    if (i < E) atomicAdd(&deg[src[i]], 1);
}

__global__ void gat_scanA(const int* __restrict__ in, int* __restrict__ bsums, int n)
{
    __shared__ int s[256];
    int t = threadIdx.x;
    int i = blockIdx.x * 256 + t;
    s[t] = (i < n) ? in[i] : 0;
    __syncthreads();
    for (int off = 128; off > 0; off >>= 1) {
        if (t < off) s[t] += s[t + off];
        __syncthreads();
    }
    if (t == 0) bsums[blockIdx.x] = s[0];
}

__global__ void gat_scanB(const int* __restrict__ bsums, int* __restrict__ bofs, int nb)
{
    __shared__ int s[512];
    int t = threadIdx.x;
    int v = (t < nb) ? bsums[t] : 0;
    s[t] = v;
    __syncthreads();
    for (int off = 1; off < 512; off <<= 1) {
        int u = (t >= off) ? s[t - off] : 0;
        __syncthreads();
        s[t] += u;
        __syncthreads();
    }
    if (t < nb) bofs[t] = s[t] - v;   // exclusive
}

__global__ void gat_scanC(const int* __restrict__ in, const int* __restrict__ bofs,
                          int* __restrict__ out, int* __restrict__ cursor, int n)
{
    __shared__ int s[256];
    int t = threadIdx.x;
    int i = blockIdx.x * 256 + t;
    int v = (i < n) ? in[i] : 0;
    s[t] = v;
    __syncthreads();
    for (int off = 1; off < 256; off <<= 1) {
        int u = (t >= off) ? s[t - off] : 0;
        __syncthreads();
        s[t] += u;
        __syncthreads();
    }
    if (i < n) {
        int excl = bofs[blockIdx.x] + s[t] - v;
        out[i] = excl;
        if (cursor) cursor[i] = excl;
        if (i == n - 1) out[n] = excl + v;
    }
}

__global__ void gat_scatter(const int* __restrict__ src, const int* __restrict__ dst,
                            const float* __restrict__ adj,
                            const float* __restrict__ f1, const float* __restrict__ f2,
                            int* __restrict__ cursor, int2* __restrict__ csr, int E)
{
    int i = blockIdx.x * blockDim.x + threadIdx.x;
    if (i >= E) return;
    int sv = src[i], dv = dst[i];
    float a = adj[i];
    float e = a * f1[sv] + a * f2[dv];
    e = (e > 0.f) ? e : ALPHA * e;
    float p = __expf(e);
    int pos = atomicAdd(&cursor[sv], 1);
    csr[pos] = make_int2(dv, __float_as_int(p));
}

// ---------------------------------------------------------------------------
// Per-node weighted gather over bf16 h. One wave per node; 4 edges per
// iteration slot (eg = lane>>4) x 16 feature quads (cg = lane&15).
// Full 64-edge tiles run a batched path: 8 (p,boff) pairs preloaded from LDS,
// then 8 INDEPENDENT uint2 h-loads issued back-to-back (x2 groups) -> ~8-16
// loads in flight per wave to hide L2/L3 latency.
// ---------------------------------------------------------------------------
__global__ __launch_bounds__(256) void gat_gather(
    const int* __restrict__ row_start, const int2* __restrict__ csr,
    const unsigned short* __restrict__ hb,
    const float* __restrict__ bias, float* __restrict__ out, int N)
{
    __shared__ float2 sh[4][64];
    const int lane = threadIdx.x & 63;
    const int wid  = threadIdx.x >> 6;
    const int node = blockIdx.x * 4 + wid;
    if (node >= N) return;

    const int cg = lane & 15;      // feature quad: cols cg*4 .. cg*4+3
    const int eg = lane >> 4;      // edge slot 0..3

    const int rs = row_start[node];
    const int re = row_start[node + 1];
    float* op = out + (long long)node * 64;
    const float4 bl4 = *(const float4*)&bias[cg * 4];

    if (re <= rs) {
        if (lane < 16) *(float4*)&op[cg * 4] = bl4;
        return;
    }

    const char* hbase = (const char*)hb + (size_t)cg * 8;

    float acc0 = 0.f, acc1 = 0.f, acc2 = 0.f, acc3 = 0.f, ssum = 0.f;
    for (int base = rs; base < re; base += 64) {
        int idx = base + lane;
        float p = 0.f;
        int boff = 0;
        if (idx < re) {
            int2 de = csr[idx];
            boff = de.x << 7;            // dst * 128 bytes (bf16 row)
            p = __int_as_float(de.y);
        }
        ssum += p;
        sh[wid][lane] = make_float2(p, __int_as_float(boff));  // padding: p=0
        __builtin_amdgcn_wave_barrier();
        __threadfence_block();           // order LDS write -> cross-lane reads
        if (re - base >= 64) {
            // full tile: 2 groups x 8 edges, loads batched for MLP
#pragma unroll
            for (int jb = 0; jb < 2; ++jb) {
                float2 bc[8];
#pragma unroll
                for (int j = 0; j < 8; ++j)
                    bc[j] = sh[wid][jb * 32 + j * 4 + eg];
                uint2 hv[8];
#pragma unroll
                for (int j = 0; j < 8; ++j)
                    hv[j] = *(const uint2*)(hbase + __float_as_int(bc[j].y));
#pragma unroll
                for (int j = 0; j < 8; ++j) {
                    float pj = bc[j].x;
                    acc0 = fmaf(pj, __uint_as_float(hv[j].x << 16), acc0);
                    acc1 = fmaf(pj, __uint_as_float(hv[j].x & 0xFFFF0000u), acc1);
                    acc2 = fmaf(pj, __uint_as_float(hv[j].y << 16), acc2);
                    acc3 = fmaf(pj, __uint_as_float(hv[j].y & 0xFFFF0000u), acc3);
                }
            }
        } else {
            int cnt = re - base;
            for (int j = 0; j < cnt; j += 4) {
                float2 bc = sh[wid][j + eg];
                float pj = bc.x;
                uint2 hv = *(const uint2*)(hbase + __float_as_int(bc.y));
                acc0 = fmaf(pj, __uint_as_float(hv.x << 16), acc0);
                acc1 = fmaf(pj, __uint_as_float(hv.x & 0xFFFF0000u), acc1);
                acc2 = fmaf(pj, __uint_as_float(hv.y << 16), acc2);
                acc3 = fmaf(pj, __uint_as_float(hv.y & 0xFFFF0000u), acc3);
            }
        }
        __builtin_amdgcn_wave_barrier();
        __threadfence_block();           // keep next write after these reads
    }
#pragma unroll
    for (int d = 32; d > 0; d >>= 1) ssum += __shfl_xor(ssum, d);
    acc0 += __shfl_xor(acc0, 16); acc0 += __shfl_xor(acc0, 32);
    acc1 += __shfl_xor(acc1, 16); acc1 += __shfl_xor(acc1, 32);
    acc2 += __shfl_xor(acc2, 16); acc2 += __shfl_xor(acc2, 32);
    acc3 += __shfl_xor(acc3, 16); acc3 += __shfl_xor(acc3, 32);

    if (lane < 16) {
        const float inv = 1.f / ssum;    // ssum > 0 (p = exp > 0)
        float4 o;
        o.x = fmaf(acc0, inv, bl4.x);
        o.y = fmaf(acc1, inv, bl4.y);
        o.z = fmaf(acc2, inv, bl4.z);
        o.w = fmaf(acc3, inv, bl4.w);
        *(float4*)&op[cg * 4] = o;
    }
}

// ---------------------------------------------------------------------------
extern "C" void kernel_launch(void* const* d_in, const int* in_sizes, int n_in,
                              void* d_out, int out_size, void* d_ws, size_t ws_size,
                              hipStream_t stream)
{
    const float* x    = (const float*)d_in[0];
    const int*   esrc = (const int*)d_in[1];
    const int*   edst = (const int*)d_in[2];
    const float* adj  = (const float*)d_in[3];
    const float* W    = (const float*)d_in[4];
    const float* a1   = (const float*)d_in[5];
    const float* a1b  = (const float*)d_in[6];
    const float* a2   = (const float*)d_in[7];
    const float* a2b  = (const float*)d_in[8];
    const float* bias = (const float*)d_in[9];
    float* out = (float*)d_out;

    const int N = in_sizes[0] / 256;
    const int E = in_sizes[1];

    const int nbuck = (N + 255) >> BUCKET_SHIFT;
    const int nblk  = (E + BW_CHUNK - 1) / BW_CHUNK;
    const int nblk2 = (E + BW2_CHUNK - 1) / BW2_CHUNK;

    // workspace carve-up
    char* p = (char*)d_ws;
    unsigned short* hbuf = (unsigned short*)p;  p += (size_t)N * 64 * 2;
    p = (char*)(((uintptr_t)p + 255) & ~(uintptr_t)255);
    float* f1  = (float*)p;  p += (size_t)N * 4;
    float* f2  = (float*)p;  p += (size_t)N * 4;
    int* deg   = (int*)p;    p += (size_t)N * 4;
    int* row_start = (int*)p; p += (size_t)(N + 1) * 4;
    p = (char*)(((uintptr_t)p + 255) & ~(uintptr_t)255);
    int* cursor = (int*)p;   p += (size_t)N * 4;       // binned: nbuck entries used
    int* bsums  = (int*)p;   p += 512 * 4;
    int* bofs   = (int*)p;   p += 512 * 4;
    p = (char*)(((uintptr_t)p + 255) & ~(uintptr_t)255);
    int* bcnt  = (int*)p;    p += 512 * 4;
    int* bbase = (int*)p;    p += 520 * 4;
    p = (char*)(((uintptr_t)p + 255) & ~(uintptr_t)255);
    int2* csr  = (int2*)p;   p += (size_t)E * 8;
    const size_t required = (size_t)(p - (char*)d_ws);

    const bool binned = (nbuck <= 512) && (required <= ws_size);

    const int nbN = (N + 255) / 256;
    const int gemm_blocks = (N + GEMM_BM - 1) / GEMM_BM;

    hipLaunchKernelGGL(gat_gemm, dim3(gemm_blocks), dim3(512), 0, stream,
                       x, W, a1, a1b, a2, a2b, hbuf, f1, f2, N);

    if (binned) {
        hipMemsetAsync(bcnt, 0, 512 * 4, stream);
        hipLaunchKernelGGL(gat_hist, dim3(nblk), dim3(512), 0, stream,
                           esrc, bcnt, E, nbuck);
        hipLaunchKernelGGL(gat_bscan, dim3(1), dim3(512), 0, stream,
                           bcnt, bbase, cursor, nbuck, E);
        hipLaunchKernelGGL(gat_binwrite, dim3(nblk2), dim3(256), 0, stream,
                           esrc, edst, adj, f1, f2, cursor, csr, E, nbuck);
        hipLaunchKernelGGL(gat_bucket_scatter, dim3(nbuck), dim3(512), 0, stream,
                           bbase, row_start, csr, N, E);
    } else {
        hipMemsetAsync(deg, 0, (size_t)N * 4, stream);
        hipLaunchKernelGGL(gat_deg, dim3((E + 255) / 256), dim3(256), 0, stream,
                           esrc, deg, E);
        hipLaunchKernelGGL(gat_scanA, dim3(nbN), dim3(256), 0, stream, deg, bsums, N);
        hipLaunchKernelGGL(gat_scanB, dim3(1), dim3(512), 0, stream, bsums, bofs, nbN);
        hipLaunchKernelGGL(gat_scanC, dim3(nbN), dim3(256), 0, stream,
                           deg, bofs, row_start, cursor, N);
        hipLaunchKernelGGL(gat_scatter, dim3((E + 255) / 256), dim3(256), 0, stream,
                           esrc, edst, adj, f1, f2, cursor, csr, E);
    }

    hipLaunchKernelGGL(gat_gather, dim3((N + 3) / 4), dim3(256), 0, stream,
                       row_start, csr, hbuf, bias, out, N);
}

// Round 11
// 218.043 us; speedup vs baseline: 1.1083x; 1.1083x over previous
//
#include <hip/hip_runtime.h>
#include <math.h>
#include <stdint.h>

#define ALPHA 0.2f
#define BW_CHUNK 8192             // edges per hist/binwrite block (16 x 512)
#define BUCKET_SHIFT 8            // 256 nodes per bucket
#define PHC_CAP 12288             // bucket LDS capacity (entries); mean ~8192, +45 sigma

typedef __attribute__((ext_vector_type(8))) short bf16x8;
typedef __attribute__((ext_vector_type(4))) float f32x4;
typedef __attribute__((ext_vector_type(8))) unsigned short u16x8;

// bf16 round-to-nearest-even
__device__ __forceinline__ unsigned short f2bf(float f)
{
    unsigned int u = __float_as_uint(f);
    unsigned int r = (u + 0x7FFFu + ((u >> 16) & 1u)) >> 16;
    return (unsigned short)r;
}

// ---------------------------------------------------------------------------
// MFMA GEMM: h = x @ W  [N,256]x[256,64] -> hb (bf16), f1/f2 from the fp32
// accumulators. 512 threads = 8 waves; tile 128 rows x 64 cols; BK=64.
// ---------------------------------------------------------------------------
#define GEMM_BM 128

__global__ __launch_bounds__(512) void gat_gemm(
    const float* __restrict__ x, const float* __restrict__ W,
    const float* __restrict__ a1, const float* __restrict__ a1b,
    const float* __restrict__ a2, const float* __restrict__ a2b,
    unsigned short* __restrict__ hb, float* __restrict__ f1, float* __restrict__ f2,
    int N)
{
    __shared__ unsigned short wt[64 * 256];   // 32 KB: wt[col][k] (swizzled)
    __shared__ unsigned short xs[128 * 64];   // 16 KB: xs[row][k-in-chunk] (swizzled)

    const int tid  = threadIdx.x;
    const int lane = tid & 63;
    const int w    = tid >> 6;                  // wave 0..7
    const int cg   = lane & 15;                 // col-in-tile / row-in-tile
    const int g    = lane >> 4;                 // quad group 0..3
    const long long row0 = (long long)blockIdx.x * GEMM_BM;

    // ---- stage W transposed (once): thread -> col c = tid>>3, k0 = (tid&7)*32
    {
        const int c  = tid >> 3;
        const int k0 = (tid & 7) * 32;
        unsigned short tmp[32];
#pragma unroll
        for (int j = 0; j < 32; ++j)
            tmp[j] = f2bf(W[(k0 + j) * 64 + c]);
        const int xorv = (c & 7) << 4;
        char* wb = (char*)wt + c * 512;
#pragma unroll
        for (int q = 0; q < 4; ++q) {
            int kbyte = (k0 + q * 8) * 2;
            *(u16x8*)(wb + (kbyte ^ xorv)) = *(u16x8*)&tmp[q * 8];
        }
    }

    f32x4 acc[4];
#pragma unroll
    for (int ct = 0; ct < 4; ++ct) acc[ct] = (f32x4){0.f, 0.f, 0.f, 0.f};

    // A-frag LDS address (constant across chunks)
    const int arow  = w * 16 + cg;
    const int axor  = (arow & 7) << 4;
    char* const abase = (char*)xs + arow * 128;

    for (int kc = 0; kc < 256; kc += 64) {
        __syncthreads();   // previous chunk's reads done (and W writes on iter 0)
        // ---- stage x chunk: 128 rows x 64 k; thread -> row tid>>2, kseg (tid&3)*16
        {
            const int r  = tid >> 2;
            const int ks = (tid & 3) * 16;
            long long gr = row0 + r;
            if (gr > (long long)N - 1) gr = (long long)N - 1;
            const float* xp = &x[gr * 256 + kc + ks];
            float4 v0 = *(const float4*)&xp[0];
            float4 v1 = *(const float4*)&xp[4];
            float4 v2 = *(const float4*)&xp[8];
            float4 v3 = *(const float4*)&xp[12];
            unsigned short tmp[16];
            tmp[0]=f2bf(v0.x); tmp[1]=f2bf(v0.y); tmp[2]=f2bf(v0.z); tmp[3]=f2bf(v0.w);
            tmp[4]=f2bf(v1.x); tmp[5]=f2bf(v1.y); tmp[6]=f2bf(v1.z); tmp[7]=f2bf(v1.w);
            tmp[8]=f2bf(v2.x); tmp[9]=f2bf(v2.y); tmp[10]=f2bf(v2.z); tmp[11]=f2bf(v2.w);
            tmp[12]=f2bf(v3.x); tmp[13]=f2bf(v3.y); tmp[14]=f2bf(v3.z); tmp[15]=f2bf(v3.w);
            const int xorv = (r & 7) << 4;
            char* xb = (char*)xs + r * 128;
            *(u16x8*)(xb + ((ks * 2) ^ xorv))      = *(u16x8*)&tmp[0];
            *(u16x8*)(xb + ((ks * 2 + 16) ^ xorv)) = *(u16x8*)&tmp[8];
        }
        __syncthreads();

#pragma unroll
        for (int s = 0; s < 2; ++s) {
            bf16x8 af = *(bf16x8*)(abase + (((s * 32 + g * 8) * 2) ^ axor));
#pragma unroll
            for (int ct = 0; ct < 4; ++ct) {
                const int col = ct * 16 + cg;
                const int kbyte = (kc + s * 32) * 2 + g * 16;
                bf16x8 bf_ = *(bf16x8*)((char*)wt + col * 512 + (kbyte ^ ((col & 7) << 4)));
                acc[ct] = __builtin_amdgcn_mfma_f32_16x16x32_bf16(af, bf_, acc[ct], 0, 0, 0);
            }
        }
    }

    // ---- epilogue: store bf16 h; f1/f2 from fp32 accumulators
    float a1v[4], a2v[4];
#pragma unroll
    for (int ct = 0; ct < 4; ++ct) {
        a1v[ct] = a1[ct * 16 + cg];
        a2v[ct] = a2[ct * 16 + cg];
    }
    const float b1 = a1b[0], b2 = a2b[0];

#pragma unroll
    for (int r = 0; r < 4; ++r) {
        const long long row = row0 + w * 16 + g * 4 + r;
        const bool ok = (row < N);
        float p1 = 0.f, p2 = 0.f;
#pragma unroll
        for (int ct = 0; ct < 4; ++ct) {
            float hv = acc[ct][r];
            if (ok) hb[row * 64 + ct * 16 + cg] = f2bf(hv);
            p1 = fmaf(hv, a1v[ct], p1);
            p2 = fmaf(hv, a2v[ct], p2);
        }
#pragma unroll
        for (int d = 8; d > 0; d >>= 1) {
            p1 += __shfl_xor(p1, d);
            p2 += __shfl_xor(p2, d);
        }
        if (ok && cg == 0) {
            f1[row] = p1 + b1;
            f2[row] = p2 + b2;
        }
    }
}

// ---------------------------------------------------------------------------
// Phase A: per-block LDS bucket histogram -> ONE global atomicAdd per bucket.
// ---------------------------------------------------------------------------
__global__ __launch_bounds__(512) void gat_hist(
    const int* __restrict__ src, int* __restrict__ bcnt, int E, int nbuck)
{
    __shared__ int hist[512];
    const int tid = threadIdx.x;
    hist[tid] = 0;
    __syncthreads();
    const long long base = (long long)blockIdx.x * BW_CHUNK;
#pragma unroll 4
    for (int k = 0; k < BW_CHUNK / 512; ++k) {
        long long i = base + k * 512 + tid;
        if (i < E) atomicAdd(&hist[src[i] >> BUCKET_SHIFT], 1);
    }
    __syncthreads();
    if (tid < nbuck && hist[tid]) atomicAdd(&bcnt[tid], hist[tid]);
}

// ---------------------------------------------------------------------------
// Single-block exclusive scan of bucket totals -> bbase[0..nbuck], cursor[].
// ---------------------------------------------------------------------------
__global__ __launch_bounds__(512) void gat_bscan(
    const int* __restrict__ bcnt, int* __restrict__ bbase,
    int* __restrict__ cursor, int nbuck, int E)
{
    __shared__ int s[512];
    const int t = threadIdx.x;
    int v = (t < nbuck) ? bcnt[t] : 0;
    s[t] = v;
    __syncthreads();
    for (int off = 1; off < 512; off <<= 1) {
        int u = (t >= off) ? s[t - off] : 0;
        __syncthreads();
        s[t] += u;
        __syncthreads();
    }
    if (t < nbuck) {
        int ex = s[t] - v;
        bbase[t]  = ex;
        cursor[t] = ex;
    }
    if (t == 0) bbase[nbuck] = E;
}

// ---------------------------------------------------------------------------
// Phase B: NO random gathers — pure streaming. pass 1: LDS bucket hist over
// src; reserve contiguous per-bucket ranges (one global atomic/bucket).
// pass 2: stream src/dst/adj, scatter payload {(dst<<8)|src_local, adj_bits}.
// The f1/f2 logit work is DEFERRED to gat_bucket_scatter, where f1 is a
// bucket-local LDS lookup and the f2 gather sits in an MLP-friendly loop.
// ---------------------------------------------------------------------------
__global__ __launch_bounds__(512) void gat_binwrite(
    const int* __restrict__ src, const int* __restrict__ dst,
    const float* __restrict__ adj,
    int* __restrict__ cursor, int2* __restrict__ bin, int E, int nbuck)
{
    __shared__ int hist[512];
    __shared__ int curs[512];
    const int tid = threadIdx.x;
    hist[tid] = 0;
    __syncthreads();

    const long long base = (long long)blockIdx.x * BW_CHUNK;
#pragma unroll 4
    for (int k = 0; k < BW_CHUNK / 512; ++k) {
        long long i = base + k * 512 + tid;
        if (i < E) atomicAdd(&hist[src[i] >> BUCKET_SHIFT], 1);
    }
    __syncthreads();
    if (tid < nbuck) {
        int c = hist[tid];
        curs[tid] = c ? atomicAdd(&cursor[tid], c) : 0;
    }
    __syncthreads();
#pragma unroll 4
    for (int k = 0; k < BW_CHUNK / 512; ++k) {
        long long i = base + k * 512 + tid;
        if (i < E) {
            int s = src[i], d = dst[i];
            float a = adj[i];
            int r = atomicAdd(&curs[s >> BUCKET_SHIFT], 1);
            bin[r] = make_int2((d << BUCKET_SHIFT) | (s & 255), __float_as_int(a));
        }
    }
}

// ---------------------------------------------------------------------------
// Phase C: one block per bucket. Preload f1 for the bucket's 256 nodes (LDS);
// local degree hist + scan writes row_start; then in-place scatter computing
// e = a*f1[s] + a*f2[d] (f2 gather = independent-iteration MLP), leaky, exp,
// -> csr {dst, p}.
// ---------------------------------------------------------------------------
__global__ __launch_bounds__(512) void gat_bucket_scatter(
    const int* __restrict__ bbase, int* __restrict__ row_start,
    const float* __restrict__ f1, const float* __restrict__ f2,
    int2* __restrict__ csr, int N, int E)
{
    __shared__ int2 buf[PHC_CAP];
    __shared__ int hist[256];     // degree hist, later reused as cursors
    __shared__ int sc[256];       // inclusive scan
    __shared__ float f1s[256];    // bucket-local f1
    const int tid = threadIdx.x;
    const int b = blockIdx.x;
    const int n0 = b << BUCKET_SHIFT;
    int n1 = n0 + 256; if (n1 > N) n1 = N;
    const int nn = n1 - n0;

    const int bstart = bbase[b];
    const int bend   = bbase[b + 1];
    int cntb = bend - bstart;
    if (cntb > PHC_CAP) cntb = PHC_CAP;           // statistically unreachable guard

    if (tid < 256) {
        hist[tid] = 0;
        f1s[tid] = (tid < nn) ? f1[n0 + tid] : 0.f;
    }
    for (int i = tid; i < cntb; i += 512) buf[i] = csr[bstart + i];
    __syncthreads();

    for (int i = tid; i < cntb; i += 512)
        atomicAdd(&hist[buf[i].x & 255], 1);
    __syncthreads();

    int v = (tid < 256) ? hist[tid] : 0;
    if (tid < 256) sc[tid] = v;
    __syncthreads();
    for (int off = 1; off < 256; off <<= 1) {
        int u = (tid < 256 && tid >= off) ? sc[tid - off] : 0;
        __syncthreads();
        if (tid < 256) sc[tid] += u;
        __syncthreads();
    }
    if (tid < 256) {
        int ex = bstart + sc[tid] - v;   // exclusive prefix + bucket base
        hist[tid] = ex;                  // reuse as cursor
        if (tid < nn) row_start[n0 + tid] = ex;
    }
    if (b == gridDim.x - 1 && tid == 0) row_start[N] = E;
    __syncthreads();

    for (int i = tid; i < cntb; i += 512) {
        int2 ev = buf[i];
        int sl = ev.x & 255;
        int dv = ev.x >> BUCKET_SHIFT;
        float a = __int_as_float(ev.y);
        float e = a * f1s[sl] + a * f2[dv];
        e = (e > 0.f) ? e : ALPHA * e;
        float p = __expf(e);
        int pos = atomicAdd(&hist[sl], 1);
        csr[pos] = make_int2(dv, __float_as_int(p));
    }
}

// ---------------------------------------------------------------------------
// Fallback kernels + generic scan (only used if bucket limits are exceeded).
// ---------------------------------------------------------------------------
__global__ void gat_deg(const int* __restrict__ src, int* __restrict__ deg, int E)
{
    int i = blockIdx.x * blockDim.x + threadIdx.x;
    if (i < E) atomicAdd(&deg[src[i]], 1);
}

__global__ void gat_scanA(const int* __restrict__ in, int* __restrict__ bsums, int n)
{
    __shared__ int s[256];
    int t = threadIdx.x;
    int i = blockIdx.x * 256 + t;
    s[t] = (i < n) ? in[i] : 0;
    __syncthreads();
    for (int off = 128; off > 0; off >>= 1) {
        if (t < off) s[t] += s[t + off];
        __syncthreads();
    }
    if (t == 0) bsums[blockIdx.x] = s[0];
}

__global__ void gat_scanB(const int* __restrict__ bsums, int* __restrict__ bofs, int nb)
{
    __shared__ int s[512];
    int t = threadIdx.x;
    int v = (t < nb) ? bsums[t] : 0;
    s[t] = v;
    __syncthreads();
    for (int off = 1; off < 512; off <<= 1) {
        int u = (t >= off) ? s[t - off] : 0;
        __syncthreads();
        s[t] += u;
        __syncthreads();
    }
    if (t < nb) bofs[t] = s[t] - v;   // exclusive
}

__global__ void gat_scanC(const int* __restrict__ in, const int* __restrict__ bofs,
                          int* __restrict__ out, int* __restrict__ cursor, int n)
{
    __shared__ int s[256];
    int t = threadIdx.x;
    int i = blockIdx.x * 256 + t;
    int v = (i < n) ? in[i] : 0;
    s[t] = v;
    __syncthreads();
    for (int off = 1; off < 256; off <<= 1) {
        int u = (t >= off) ? s[t - off] : 0;
        __syncthreads();
        s[t] += u;
        __syncthreads();
    }
    if (i < n) {
        int excl = bofs[blockIdx.x] + s[t] - v;
        out[i] = excl;
        if (cursor) cursor[i] = excl;
        if (i == n - 1) out[n] = excl + v;
    }
}

__global__ void gat_scatter(const int* __restrict__ src, const int* __restrict__ dst,
                            const float* __restrict__ adj,
                            const float* __restrict__ f1, const float* __restrict__ f2,
                            int* __restrict__ cursor, int2* __restrict__ csr, int E)
{
    int i = blockIdx.x * blockDim.x + threadIdx.x;
    if (i >= E) return;
    int sv = src[i], dv = dst[i];
    float a = adj[i];
    float e = a * f1[sv] + a * f2[dv];
    e = (e > 0.f) ? e : ALPHA * e;
    float p = __expf(e);
    int pos = atomicAdd(&cursor[sv], 1);
    csr[pos] = make_int2(dv, __float_as_int(p));
}

// ---------------------------------------------------------------------------
// Per-node weighted gather over bf16 h. One wave per node; 4 edges per
// iteration slot (eg = lane>>4) x 16 feature quads (cg = lane&15).
// Full 64-edge tiles run a batched path: 8 (p,boff) pairs preloaded from LDS,
// then 8 INDEPENDENT uint2 h-loads issued back-to-back (x2 groups) -> ~8-16
// loads in flight per wave to hide L2/L3 latency.
// ---------------------------------------------------------------------------
__global__ __launch_bounds__(256) void gat_gather(
    const int* __restrict__ row_start, const int2* __restrict__ csr,
    const unsigned short* __restrict__ hb,
    const float* __restrict__ bias, float* __restrict__ out, int N)
{
    __shared__ float2 sh[4][64];
    const int lane = threadIdx.x & 63;
    const int wid  = threadIdx.x >> 6;
    const int node = blockIdx.x * 4 + wid;
    if (node >= N) return;

    const int cg = lane & 15;      // feature quad: cols cg*4 .. cg*4+3
    const int eg = lane >> 4;      // edge slot 0..3

    const int rs = row_start[node];
    const int re = row_start[node + 1];
    float* op = out + (long long)node * 64;
    const float4 bl4 = *(const float4*)&bias[cg * 4];

    if (re <= rs) {
        if (lane < 16) *(float4*)&op[cg * 4] = bl4;
        return;
    }

    const char* hbase = (const char*)hb + (size_t)cg * 8;

    float acc0 = 0.f, acc1 = 0.f, acc2 = 0.f, acc3 = 0.f, ssum = 0.f;
    for (int base = rs; base < re; base += 64) {
        int idx = base + lane;
        float p = 0.f;
        int boff = 0;
        if (idx < re) {
            int2 de = csr[idx];
            boff = de.x << 7;            // dst * 128 bytes (bf16 row)
            p = __int_as_float(de.y);
        }
        ssum += p;
        sh[wid][lane] = make_float2(p, __int_as_float(boff));  // padding: p=0
        __builtin_amdgcn_wave_barrier();
        __threadfence_block();           // order LDS write -> cross-lane reads
        if (re - base >= 64) {
            // full tile: 2 groups x 8 edges, loads batched for MLP
#pragma unroll
            for (int jb = 0; jb < 2; ++jb) {
                float2 bc[8];
#pragma unroll
                for (int j = 0; j < 8; ++j)
                    bc[j] = sh[wid][jb * 32 + j * 4 + eg];
                uint2 hv[8];
#pragma unroll
                for (int j = 0; j < 8; ++j)
                    hv[j] = *(const uint2*)(hbase + __float_as_int(bc[j].y));
#pragma unroll
                for (int j = 0; j < 8; ++j) {
                    float pj = bc[j].x;
                    acc0 = fmaf(pj, __uint_as_float(hv[j].x << 16), acc0);
                    acc1 = fmaf(pj, __uint_as_float(hv[j].x & 0xFFFF0000u), acc1);
                    acc2 = fmaf(pj, __uint_as_float(hv[j].y << 16), acc2);
                    acc3 = fmaf(pj, __uint_as_float(hv[j].y & 0xFFFF0000u), acc3);
                }
            }
        } else {
            int cnt = re - base;
            for (int j = 0; j < cnt; j += 4) {
                float2 bc = sh[wid][j + eg];
                float pj = bc.x;
                uint2 hv = *(const uint2*)(hbase + __float_as_int(bc.y));
                acc0 = fmaf(pj, __uint_as_float(hv.x << 16), acc0);
                acc1 = fmaf(pj, __uint_as_float(hv.x & 0xFFFF0000u), acc1);
                acc2 = fmaf(pj, __uint_as_float(hv.y << 16), acc2);
                acc3 = fmaf(pj, __uint_as_float(hv.y & 0xFFFF0000u), acc3);
            }
        }
        __builtin_amdgcn_wave_barrier();
        __threadfence_block();           // keep next write after these reads
    }
#pragma unroll
    for (int d = 32; d > 0; d >>= 1) ssum += __shfl_xor(ssum, d);
    acc0 += __shfl_xor(acc0, 16); acc0 += __shfl_xor(acc0, 32);
    acc1 += __shfl_xor(acc1, 16); acc1 += __shfl_xor(acc1, 32);
    acc2 += __shfl_xor(acc2, 16); acc2 += __shfl_xor(acc2, 32);
    acc3 += __shfl_xor(acc3, 16); acc3 += __shfl_xor(acc3, 32);

    if (lane < 16) {
        const float inv = 1.f / ssum;    // ssum > 0 (p = exp > 0)
        float4 o;
        o.x = fmaf(acc0, inv, bl4.x);
        o.y = fmaf(acc1, inv, bl4.y);
        o.z = fmaf(acc2, inv, bl4.z);
        o.w = fmaf(acc3, inv, bl4.w);
        *(float4*)&op[cg * 4] = o;
    }
}

// ---------------------------------------------------------------------------
extern "C" void kernel_launch(void* const* d_in, const int* in_sizes, int n_in,
                              void* d_out, int out_size, void* d_ws, size_t ws_size,
                              hipStream_t stream)
{
    const float* x    = (const float*)d_in[0];
    const int*   esrc = (const int*)d_in[1];
    const int*   edst = (const int*)d_in[2];
    const float* adj  = (const float*)d_in[3];
    const float* W    = (const float*)d_in[4];
    const float* a1   = (const float*)d_in[5];
    const float* a1b  = (const float*)d_in[6];
    const float* a2   = (const float*)d_in[7];
    const float* a2b  = (const float*)d_in[8];
    const float* bias = (const float*)d_in[9];
    float* out = (float*)d_out;

    const int N = in_sizes[0] / 256;
    const int E = in_sizes[1];

    const int nbuck = (N + 255) >> BUCKET_SHIFT;
    const int nblk  = (E + BW_CHUNK - 1) / BW_CHUNK;

    // workspace carve-up
    char* p = (char*)d_ws;
    unsigned short* hbuf = (unsigned short*)p;  p += (size_t)N * 64 * 2;
    p = (char*)(((uintptr_t)p + 255) & ~(uintptr_t)255);
    float* f1  = (float*)p;  p += (size_t)N * 4;
    float* f2  = (float*)p;  p += (size_t)N * 4;
    int* deg   = (int*)p;    p += (size_t)N * 4;
    int* row_start = (int*)p; p += (size_t)(N + 1) * 4;
    p = (char*)(((uintptr_t)p + 255) & ~(uintptr_t)255);
    int* cursor = (int*)p;   p += (size_t)N * 4;       // binned: nbuck entries used
    int* bsums  = (int*)p;   p += 512 * 4;
    int* bofs   = (int*)p;   p += 512 * 4;
    p = (char*)(((uintptr_t)p + 255) & ~(uintptr_t)255);
    int* bcnt  = (int*)p;    p += 512 * 4;
    int* bbase = (int*)p;    p += 520 * 4;
    p = (char*)(((uintptr_t)p + 255) & ~(uintptr_t)255);
    int2* csr  = (int2*)p;   p += (size_t)E * 8;
    const size_t required = (size_t)(p - (char*)d_ws);

    const bool binned = (nbuck <= 512) && (required <= ws_size);

    const int nbN = (N + 255) / 256;
    const int gemm_blocks = (N + GEMM_BM - 1) / GEMM_BM;

    hipLaunchKernelGGL(gat_gemm, dim3(gemm_blocks), dim3(512), 0, stream,
                       x, W, a1, a1b, a2, a2b, hbuf, f1, f2, N);

    if (binned) {
        hipMemsetAsync(bcnt, 0, 512 * 4, stream);
        hipLaunchKernelGGL(gat_hist, dim3(nblk), dim3(512), 0, stream,
                           esrc, bcnt, E, nbuck);
        hipLaunchKernelGGL(gat_bscan, dim3(1), dim3(512), 0, stream,
                           bcnt, bbase, cursor, nbuck, E);
        hipLaunchKernelGGL(gat_binwrite, dim3(nblk), dim3(512), 0, stream,
                           esrc, edst, adj, cursor, csr, E, nbuck);
        hipLaunchKernelGGL(gat_bucket_scatter, dim3(nbuck), dim3(512), 0, stream,
                           bbase, row_start, f1, f2, csr, N, E);
    } else {
        hipMemsetAsync(deg, 0, (size_t)N * 4, stream);
        hipLaunchKernelGGL(gat_deg, dim3((E + 255) / 256), dim3(256), 0, stream,
                           esrc, deg, E);
        hipLaunchKernelGGL(gat_scanA, dim3(nbN), dim3(256), 0, stream, deg, bsums, N);
        hipLaunchKernelGGL(gat_scanB, dim3(1), dim3(512), 0, stream, bsums, bofs, nbN);
        hipLaunchKernelGGL(gat_scanC, dim3(nbN), dim3(256), 0, stream,
                           deg, bofs, row_start, cursor, N);
        hipLaunchKernelGGL(gat_scatter, dim3((E + 255) / 256), dim3(256), 0, stream,
                           esrc, edst, adj, f1, f2, cursor, csr, E);
    }

    hipLaunchKernelGGL(gat_gather, dim3((N + 3) / 4), dim3(256), 0, stream,
                       row_start, csr, hbuf, bias, out, N);
}

// Round 12
// 187.250 us; speedup vs baseline: 1.2906x; 1.1644x over previous
//
#include <hip/hip_runtime.h>
#include <math.h>
#include <stdint.h>

#define ALPHA 0.2f
#define BW_CHUNK 8192             // edges per hist/binwrite block (16 x 512)
#define BUCKET_SHIFT 8            // 256 nodes per bucket
#define PHC_CAP 12288             // bucket LDS capacity (entries); mean ~8192, +45 sigma

typedef __attribute__((ext_vector_type(8))) short bf16x8;
typedef __attribute__((ext_vector_type(4))) float f32x4;
typedef __attribute__((ext_vector_type(8))) unsigned short u16x8;

// bf16 round-to-nearest-even
__device__ __forceinline__ unsigned short f2bf(float f)
{
    unsigned int u = __float_as_uint(f);
    unsigned int r = (u + 0x7FFFu + ((u >> 16) & 1u)) >> 16;
    return (unsigned short)r;
}

// ---------------------------------------------------------------------------
// MFMA GEMM: h = x @ W  [N,256]x[256,64] -> hb (bf16), f1/f2 from the fp32
// accumulators. 512 threads = 8 waves; tile 128 rows x 64 cols; BK=64.
// ---------------------------------------------------------------------------
#define GEMM_BM 128

__global__ __launch_bounds__(512) void gat_gemm(
    const float* __restrict__ x, const float* __restrict__ W,
    const float* __restrict__ a1, const float* __restrict__ a1b,
    const float* __restrict__ a2, const float* __restrict__ a2b,
    unsigned short* __restrict__ hb, float* __restrict__ f1, float* __restrict__ f2,
    int N)
{
    __shared__ unsigned short wt[64 * 256];   // 32 KB: wt[col][k] (swizzled)
    __shared__ unsigned short xs[128 * 64];   // 16 KB: xs[row][k-in-chunk] (swizzled)

    const int tid  = threadIdx.x;
    const int lane = tid & 63;
    const int w    = tid >> 6;                  // wave 0..7
    const int cg   = lane & 15;                 // col-in-tile / row-in-tile
    const int g    = lane >> 4;                 // quad group 0..3
    const long long row0 = (long long)blockIdx.x * GEMM_BM;

    // ---- stage W transposed (once): thread -> col c = tid>>3, k0 = (tid&7)*32
    {
        const int c  = tid >> 3;
        const int k0 = (tid & 7) * 32;
        unsigned short tmp[32];
#pragma unroll
        for (int j = 0; j < 32; ++j)
            tmp[j] = f2bf(W[(k0 + j) * 64 + c]);
        const int xorv = (c & 7) << 4;
        char* wb = (char*)wt + c * 512;
#pragma unroll
        for (int q = 0; q < 4; ++q) {
            int kbyte = (k0 + q * 8) * 2;
            *(u16x8*)(wb + (kbyte ^ xorv)) = *(u16x8*)&tmp[q * 8];
        }
    }

    f32x4 acc[4];
#pragma unroll
    for (int ct = 0; ct < 4; ++ct) acc[ct] = (f32x4){0.f, 0.f, 0.f, 0.f};

    // A-frag LDS address (constant across chunks)
    const int arow  = w * 16 + cg;
    const int axor  = (arow & 7) << 4;
    char* const abase = (char*)xs + arow * 128;

    for (int kc = 0; kc < 256; kc += 64) {
        __syncthreads();   // previous chunk's reads done (and W writes on iter 0)
        // ---- stage x chunk: 128 rows x 64 k; thread -> row tid>>2, kseg (tid&3)*16
        {
            const int r  = tid >> 2;
            const int ks = (tid & 3) * 16;
            long long gr = row0 + r;
            if (gr > (long long)N - 1) gr = (long long)N - 1;
            const float* xp = &x[gr * 256 + kc + ks];
            float4 v0 = *(const float4*)&xp[0];
            float4 v1 = *(const float4*)&xp[4];
            float4 v2 = *(const float4*)&xp[8];
            float4 v3 = *(const float4*)&xp[12];
            unsigned short tmp[16];
            tmp[0]=f2bf(v0.x); tmp[1]=f2bf(v0.y); tmp[2]=f2bf(v0.z); tmp[3]=f2bf(v0.w);
            tmp[4]=f2bf(v1.x); tmp[5]=f2bf(v1.y); tmp[6]=f2bf(v1.z); tmp[7]=f2bf(v1.w);
            tmp[8]=f2bf(v2.x); tmp[9]=f2bf(v2.y); tmp[10]=f2bf(v2.z); tmp[11]=f2bf(v2.w);
            tmp[12]=f2bf(v3.x); tmp[13]=f2bf(v3.y); tmp[14]=f2bf(v3.z); tmp[15]=f2bf(v3.w);
            const int xorv = (r & 7) << 4;
            char* xb = (char*)xs + r * 128;
            *(u16x8*)(xb + ((ks * 2) ^ xorv))      = *(u16x8*)&tmp[0];
            *(u16x8*)(xb + ((ks * 2 + 16) ^ xorv)) = *(u16x8*)&tmp[8];
        }
        __syncthreads();

#pragma unroll
        for (int s = 0; s < 2; ++s) {
            bf16x8 af = *(bf16x8*)(abase + (((s * 32 + g * 8) * 2) ^ axor));
#pragma unroll
            for (int ct = 0; ct < 4; ++ct) {
                const int col = ct * 16 + cg;
                const int kbyte = (kc + s * 32) * 2 + g * 16;
                bf16x8 bf_ = *(bf16x8*)((char*)wt + col * 512 + (kbyte ^ ((col & 7) << 4)));
                acc[ct] = __builtin_amdgcn_mfma_f32_16x16x32_bf16(af, bf_, acc[ct], 0, 0, 0);
            }
        }
    }

    // ---- epilogue: store bf16 h; f1/f2 from fp32 accumulators
    float a1v[4], a2v[4];
#pragma unroll
    for (int ct = 0; ct < 4; ++ct) {
        a1v[ct] = a1[ct * 16 + cg];
        a2v[ct] = a2[ct * 16 + cg];
    }
    const float b1 = a1b[0], b2 = a2b[0];

#pragma unroll
    for (int r = 0; r < 4; ++r) {
        const long long row = row0 + w * 16 + g * 4 + r;
        const bool ok = (row < N);
        float p1 = 0.f, p2 = 0.f;
#pragma unroll
        for (int ct = 0; ct < 4; ++ct) {
            float hv = acc[ct][r];
            if (ok) hb[row * 64 + ct * 16 + cg] = f2bf(hv);
            p1 = fmaf(hv, a1v[ct], p1);
            p2 = fmaf(hv, a2v[ct], p2);
        }
#pragma unroll
        for (int d = 8; d > 0; d >>= 1) {
            p1 += __shfl_xor(p1, d);
            p2 += __shfl_xor(p2, d);
        }
        if (ok && cg == 0) {
            f1[row] = p1 + b1;
            f2[row] = p2 + b2;
        }
    }
}

// ---------------------------------------------------------------------------
// Phase A: per-block LDS bucket histogram -> ONE global atomicAdd per bucket.
// ---------------------------------------------------------------------------
__global__ __launch_bounds__(512) void gat_hist(
    const int* __restrict__ src, int* __restrict__ bcnt, int E, int nbuck)
{
    __shared__ int hist[512];
    const int tid = threadIdx.x;
    hist[tid] = 0;
    __syncthreads();
    const long long base = (long long)blockIdx.x * BW_CHUNK;
#pragma unroll 4
    for (int k = 0; k < BW_CHUNK / 512; ++k) {
        long long i = base + k * 512 + tid;
        if (i < E) atomicAdd(&hist[src[i] >> BUCKET_SHIFT], 1);
    }
    __syncthreads();
    if (tid < nbuck && hist[tid]) atomicAdd(&bcnt[tid], hist[tid]);
}

// ---------------------------------------------------------------------------
// Single-block exclusive scan of bucket totals -> bbase[0..nbuck], cursor[].
// ---------------------------------------------------------------------------
__global__ __launch_bounds__(512) void gat_bscan(
    const int* __restrict__ bcnt, int* __restrict__ bbase,
    int* __restrict__ cursor, int nbuck, int E)
{
    __shared__ int s[512];
    const int t = threadIdx.x;
    int v = (t < nbuck) ? bcnt[t] : 0;
    s[t] = v;
    __syncthreads();
    for (int off = 1; off < 512; off <<= 1) {
        int u = (t >= off) ? s[t - off] : 0;
        __syncthreads();
        s[t] += u;
        __syncthreads();
    }
    if (t < nbuck) {
        int ex = s[t] - v;
        bbase[t]  = ex;
        cursor[t] = ex;
    }
    if (t == 0) bbase[nbuck] = E;
}

// ---------------------------------------------------------------------------
// Phase B: NO random gathers — pure streaming. pass 1: LDS bucket hist over
// src; reserve contiguous per-bucket ranges (one global atomic/bucket).
// pass 2: stream src/dst/adj, scatter payload {(dst<<8)|src_local, adj_bits}.
// ---------------------------------------------------------------------------
__global__ __launch_bounds__(512) void gat_binwrite(
    const int* __restrict__ src, const int* __restrict__ dst,
    const float* __restrict__ adj,
    int* __restrict__ cursor, int2* __restrict__ bin, int E, int nbuck)
{
    __shared__ int hist[512];
    __shared__ int curs[512];
    const int tid = threadIdx.x;
    hist[tid] = 0;
    __syncthreads();

    const long long base = (long long)blockIdx.x * BW_CHUNK;
#pragma unroll 4
    for (int k = 0; k < BW_CHUNK / 512; ++k) {
        long long i = base + k * 512 + tid;
        if (i < E) atomicAdd(&hist[src[i] >> BUCKET_SHIFT], 1);
    }
    __syncthreads();
    if (tid < nbuck) {
        int c = hist[tid];
        curs[tid] = c ? atomicAdd(&cursor[tid], c) : 0;
    }
    __syncthreads();
#pragma unroll 4
    for (int k = 0; k < BW_CHUNK / 512; ++k) {
        long long i = base + k * 512 + tid;
        if (i < E) {
            int s = src[i], d = dst[i];
            float a = adj[i];
            int r = atomicAdd(&curs[s >> BUCKET_SHIFT], 1);
            bin[r] = make_int2((d << BUCKET_SHIFT) | (s & 255), __float_as_int(a));
        }
    }
}

// ---------------------------------------------------------------------------
// Phase C: one block per bucket. Preload f1 for the bucket's 256 nodes (LDS);
// local degree hist + scan writes row_start; then in-place scatter computing
// e = a*f1[s] + a*f2[d] (f2 gather = independent-iteration MLP), leaky, exp,
// -> csr {dst, p}.
// ---------------------------------------------------------------------------
__global__ __launch_bounds__(512) void gat_bucket_scatter(
    const int* __restrict__ bbase, int* __restrict__ row_start,
    const float* __restrict__ f1, const float* __restrict__ f2,
    int2* __restrict__ csr, int N, int E)
{
    __shared__ int2 buf[PHC_CAP];
    __shared__ int hist[256];     // degree hist, later reused as cursors
    __shared__ int sc[256];       // inclusive scan
    __shared__ float f1s[256];    // bucket-local f1
    const int tid = threadIdx.x;
    const int b = blockIdx.x;
    const int n0 = b << BUCKET_SHIFT;
    int n1 = n0 + 256; if (n1 > N) n1 = N;
    const int nn = n1 - n0;

    const int bstart = bbase[b];
    const int bend   = bbase[b + 1];
    int cntb = bend - bstart;
    if (cntb > PHC_CAP) cntb = PHC_CAP;           // statistically unreachable guard

    if (tid < 256) {
        hist[tid] = 0;
        f1s[tid] = (tid < nn) ? f1[n0 + tid] : 0.f;
    }
    for (int i = tid; i < cntb; i += 512) buf[i] = csr[bstart + i];
    __syncthreads();

    for (int i = tid; i < cntb; i += 512)
        atomicAdd(&hist[buf[i].x & 255], 1);
    __syncthreads();

    int v = (tid < 256) ? hist[tid] : 0;
    if (tid < 256) sc[tid] = v;
    __syncthreads();
    for (int off = 1; off < 256; off <<= 1) {
        int u = (tid < 256 && tid >= off) ? sc[tid - off] : 0;
        __syncthreads();
        if (tid < 256) sc[tid] += u;
        __syncthreads();
    }
    if (tid < 256) {
        int ex = bstart + sc[tid] - v;   // exclusive prefix + bucket base
        hist[tid] = ex;                  // reuse as cursor
        if (tid < nn) row_start[n0 + tid] = ex;
    }
    if (b == gridDim.x - 1 && tid == 0) row_start[N] = E;
    __syncthreads();

    for (int i = tid; i < cntb; i += 512) {
        int2 ev = buf[i];
        int sl = ev.x & 255;
        int dv = ev.x >> BUCKET_SHIFT;
        float a = __int_as_float(ev.y);
        float e = a * f1s[sl] + a * f2[dv];
        e = (e > 0.f) ? e : ALPHA * e;
        float p = __expf(e);
        int pos = atomicAdd(&hist[sl], 1);
        csr[pos] = make_int2(dv, __float_as_int(p));
    }
}

// ---------------------------------------------------------------------------
// Fallback kernels + generic scan (only used if bucket limits are exceeded).
// ---------------------------------------------------------------------------
__global__ void gat_deg(const int* __restrict__ src, int* __restrict__ deg, int E)
{
    int i = blockIdx.x * blockDim.x + threadIdx.x;
    if (i < E) atomicAdd(&deg[src[i]], 1);
}

__global__ void gat_scanA(const int* __restrict__ in, int* __restrict__ bsums, int n)
{
    __shared__ int s[256];
    int t = threadIdx.x;
    int i = blockIdx.x * 256 + t;
    s[t] = (i < n) ? in[i] : 0;
    __syncthreads();
    for (int off = 128; off > 0; off >>= 1) {
        if (t < off) s[t] += s[t + off];
        __syncthreads();
    }
    if (t == 0) bsums[blockIdx.x] = s[0];
}

__global__ void gat_scanB(const int* __restrict__ bsums, int* __restrict__ bofs, int nb)
{
    __shared__ int s[512];
    int t = threadIdx.x;
    int v = (t < nb) ? bsums[t] : 0;
    s[t] = v;
    __syncthreads();
    for (int off = 1; off < 512; off <<= 1) {
        int u = (t >= off) ? s[t - off] : 0;
        __syncthreads();
        s[t] += u;
        __syncthreads();
    }
    if (t < nb) bofs[t] = s[t] - v;   // exclusive
}

__global__ void gat_scanC(const int* __restrict__ in, const int* __restrict__ bofs,
                          int* __restrict__ out, int* __restrict__ cursor, int n)
{
    __shared__ int s[256];
    int t = threadIdx.x;
    int i = blockIdx.x * 256 + t;
    int v = (i < n) ? in[i] : 0;
    s[t] = v;
    __syncthreads();
    for (int off = 1; off < 256; off <<= 1) {
        int u = (t >= off) ? s[t - off] : 0;
        __syncthreads();
        s[t] += u;
        __syncthreads();
    }
    if (i < n) {
        int excl = bofs[blockIdx.x] + s[t] - v;
        out[i] = excl;
        if (cursor) cursor[i] = excl;
        if (i == n - 1) out[n] = excl + v;
    }
}

__global__ void gat_scatter(const int* __restrict__ src, const int* __restrict__ dst,
                            const float* __restrict__ adj,
                            const float* __restrict__ f1, const float* __restrict__ f2,
                            int* __restrict__ cursor, int2* __restrict__ csr, int E)
{
    int i = blockIdx.x * blockDim.x + threadIdx.x;
    if (i >= E) return;
    int sv = src[i], dv = dst[i];
    float a = adj[i];
    float e = a * f1[sv] + a * f2[dv];
    e = (e > 0.f) ? e : ALPHA * e;
    float p = __expf(e);
    int pos = atomicAdd(&cursor[sv], 1);
    csr[pos] = make_int2(dv, __float_as_int(p));
}

// ---------------------------------------------------------------------------
// Per-node weighted gather over bf16 h. One wave per node; 4 edges per
// iteration slot (eg = lane>>4) x 16 feature quads (cg = lane&15).
// Round-9 structure (VGPR ~16-24, high occupancy) + unroll x2: two
// independent (bc, hv) pairs in flight per wave. LDS strip padding always
// carries p=0/boff=0, so the second pair may read past cnt safely.
// ---------------------------------------------------------------------------
__global__ __launch_bounds__(256) void gat_gather(
    const int* __restrict__ row_start, const int2* __restrict__ csr,
    const unsigned short* __restrict__ hb,
    const float* __restrict__ bias, float* __restrict__ out, int N)
{
    __shared__ float2 sh[4][64];
    const int lane = threadIdx.x & 63;
    const int wid  = threadIdx.x >> 6;
    const int node = blockIdx.x * 4 + wid;
    if (node >= N) return;

    const int cg = lane & 15;      // feature quad: cols cg*4 .. cg*4+3
    const int eg = lane >> 4;      // edge slot 0..3

    const int rs = row_start[node];
    const int re = row_start[node + 1];
    float* op = out + (long long)node * 64;
    const float4 bl4 = *(const float4*)&bias[cg * 4];

    if (re <= rs) {
        if (lane < 16) *(float4*)&op[cg * 4] = bl4;
        return;
    }

    const char* hbase = (const char*)hb + (size_t)cg * 8;

    float acc0 = 0.f, acc1 = 0.f, acc2 = 0.f, acc3 = 0.f, ssum = 0.f;
    for (int base = rs; base < re; base += 64) {
        int idx = base + lane;
        float p = 0.f;
        int boff = 0;
        if (idx < re) {
            int2 de = csr[idx];
            boff = de.x << 7;            // dst * 128 bytes (bf16 row)
            p = __int_as_float(de.y);
        }
        ssum += p;
        sh[wid][lane] = make_float2(p, __int_as_float(boff));  // padding: p=0
        __builtin_amdgcn_wave_barrier();
        __threadfence_block();           // order LDS write -> cross-lane reads
        int cnt = re - base; if (cnt > 64) cnt = 64;
        for (int j = 0; j < cnt; j += 8) {
            float2 bcA = sh[wid][j + eg];
            float2 bcB = sh[wid][j + 4 + eg];        // may be padding: p=0, safe
            uint2 hvA = *(const uint2*)(hbase + __float_as_int(bcA.y));
            uint2 hvB = *(const uint2*)(hbase + __float_as_int(bcB.y));
            float pA = bcA.x, pB = bcB.x;
            acc0 = fmaf(pA, __uint_as_float(hvA.x << 16), acc0);
            acc1 = fmaf(pA, __uint_as_float(hvA.x & 0xFFFF0000u), acc1);
            acc2 = fmaf(pA, __uint_as_float(hvA.y << 16), acc2);
            acc3 = fmaf(pA, __uint_as_float(hvA.y & 0xFFFF0000u), acc3);
            acc0 = fmaf(pB, __uint_as_float(hvB.x << 16), acc0);
            acc1 = fmaf(pB, __uint_as_float(hvB.x & 0xFFFF0000u), acc1);
            acc2 = fmaf(pB, __uint_as_float(hvB.y << 16), acc2);
            acc3 = fmaf(pB, __uint_as_float(hvB.y & 0xFFFF0000u), acc3);
        }
        __builtin_amdgcn_wave_barrier();
        __threadfence_block();           // keep next write after these reads
    }
#pragma unroll
    for (int d = 32; d > 0; d >>= 1) ssum += __shfl_xor(ssum, d);
    acc0 += __shfl_xor(acc0, 16); acc0 += __shfl_xor(acc0, 32);
    acc1 += __shfl_xor(acc1, 16); acc1 += __shfl_xor(acc1, 32);
    acc2 += __shfl_xor(acc2, 16); acc2 += __shfl_xor(acc2, 32);
    acc3 += __shfl_xor(acc3, 16); acc3 += __shfl_xor(acc3, 32);

    if (lane < 16) {
        const float inv = 1.f / ssum;    // ssum > 0 (p = exp > 0)
        float4 o;
        o.x = fmaf(acc0, inv, bl4.x);
        o.y = fmaf(acc1, inv, bl4.y);
        o.z = fmaf(acc2, inv, bl4.z);
        o.w = fmaf(acc3, inv, bl4.w);
        *(float4*)&op[cg * 4] = o;
    }
}

// ---------------------------------------------------------------------------
extern "C" void kernel_launch(void* const* d_in, const int* in_sizes, int n_in,
                              void* d_out, int out_size, void* d_ws, size_t ws_size,
                              hipStream_t stream)
{
    const float* x    = (const float*)d_in[0];
    const int*   esrc = (const int*)d_in[1];
    const int*   edst = (const int*)d_in[2];
    const float* adj  = (const float*)d_in[3];
    const float* W    = (const float*)d_in[4];
    const float* a1   = (const float*)d_in[5];
    const float* a1b  = (const float*)d_in[6];
    const float* a2   = (const float*)d_in[7];
    const float* a2b  = (const float*)d_in[8];
    const float* bias = (const float*)d_in[9];
    float* out = (float*)d_out;

    const int N = in_sizes[0] / 256;
    const int E = in_sizes[1];

    const int nbuck = (N + 255) >> BUCKET_SHIFT;
    const int nblk  = (E + BW_CHUNK - 1) / BW_CHUNK;

    // workspace carve-up
    char* p = (char*)d_ws;
    unsigned short* hbuf = (unsigned short*)p;  p += (size_t)N * 64 * 2;
    p = (char*)(((uintptr_t)p + 255) & ~(uintptr_t)255);
    float* f1  = (float*)p;  p += (size_t)N * 4;
    float* f2  = (float*)p;  p += (size_t)N * 4;
    int* deg   = (int*)p;    p += (size_t)N * 4;
    int* row_start = (int*)p; p += (size_t)(N + 1) * 4;
    p = (char*)(((uintptr_t)p + 255) & ~(uintptr_t)255);
    int* cursor = (int*)p;   p += (size_t)N * 4;       // binned: nbuck entries used
    int* bsums  = (int*)p;   p += 512 * 4;
    int* bofs   = (int*)p;   p += 512 * 4;
    p = (char*)(((uintptr_t)p + 255) & ~(uintptr_t)255);
    int* bcnt  = (int*)p;    p += 512 * 4;
    int* bbase = (int*)p;    p += 520 * 4;
    p = (char*)(((uintptr_t)p + 255) & ~(uintptr_t)255);
    int2* csr  = (int2*)p;   p += (size_t)E * 8;
    const size_t required = (size_t)(p - (char*)d_ws);

    const bool binned = (nbuck <= 512) && (required <= ws_size);

    const int nbN = (N + 255) / 256;
    const int gemm_blocks = (N + GEMM_BM - 1) / GEMM_BM;

    hipLaunchKernelGGL(gat_gemm, dim3(gemm_blocks), dim3(512), 0, stream,
                       x, W, a1, a1b, a2, a2b, hbuf, f1, f2, N);

    if (binned) {
        hipMemsetAsync(bcnt, 0, 512 * 4, stream);
        hipLaunchKernelGGL(gat_hist, dim3(nblk), dim3(512), 0, stream,
                           esrc, bcnt, E, nbuck);
        hipLaunchKernelGGL(gat_bscan, dim3(1), dim3(512), 0, stream,
                           bcnt, bbase, cursor, nbuck, E);
        hipLaunchKernelGGL(gat_binwrite, dim3(nblk), dim3(512), 0, stream,
                           esrc, edst, adj, cursor, csr, E, nbuck);
        hipLaunchKernelGGL(gat_bucket_scatter, dim3(nbuck), dim3(512), 0, stream,
                           bbase, row_start, f1, f2, csr, N, E);
    } else {
        hipMemsetAsync(deg, 0, (size_t)N * 4, stream);
        hipLaunchKernelGGL(gat_deg, dim3((E + 255) / 256), dim3(256), 0, stream,
                           esrc, deg, E);
        hipLaunchKernelGGL(gat_scanA, dim3(nbN), dim3(256), 0, stream, deg, bsums, N);
        hipLaunchKernelGGL(gat_scanB, dim3(1), dim3(512), 0, stream, bsums, bofs, nbN);
        hipLaunchKernelGGL(gat_scanC, dim3(nbN), dim3(256), 0, stream,
                           deg, bofs, row_start, cursor, N);
        hipLaunchKernelGGL(gat_scatter, dim3((E + 255) / 256), dim3(256), 0, stream,
                           esrc, edst, adj, f1, f2, cursor, csr, E);
    }

    hipLaunchKernelGGL(gat_gather, dim3((N + 3) / 4), dim3(256), 0, stream,
                       row_start, csr, hbuf, bias, out, N);
}

// Round 13
// 181.012 us; speedup vs baseline: 1.3351x; 1.0345x over previous
//
#include <hip/hip_runtime.h>
#include <math.h>
#include <stdint.h>

#define ALPHA 0.2f
#define BW_CHUNK 8192             // edges per hist/binwrite block (16 x 512)
#define BUCKET_SHIFT 8            // 256 nodes per bucket
#define PHC_CAP 12288             // bucket LDS capacity (entries); mean ~8192, +45 sigma

typedef __attribute__((ext_vector_type(8))) short bf16x8;
typedef __attribute__((ext_vector_type(4))) float f32x4;
typedef __attribute__((ext_vector_type(8))) unsigned short u16x8;

// bf16 round-to-nearest-even
__device__ __forceinline__ unsigned short f2bf(float f)
{
    unsigned int u = __float_as_uint(f);
    unsigned int r = (u + 0x7FFFu + ((u >> 16) & 1u)) >> 16;
    return (unsigned short)r;
}

// ---------------------------------------------------------------------------
// MFMA GEMM: h = x @ W  [N,256]x[256,64] -> hb (bf16), f1/f2 from the fp32
// accumulators. 512 threads = 8 waves; tile 128 rows x 64 cols; BK=64.
// ---------------------------------------------------------------------------
#define GEMM_BM 128

__global__ __launch_bounds__(512) void gat_gemm(
    const float* __restrict__ x, const float* __restrict__ W,
    const float* __restrict__ a1, const float* __restrict__ a1b,
    const float* __restrict__ a2, const float* __restrict__ a2b,
    unsigned short* __restrict__ hb, float* __restrict__ f1, float* __restrict__ f2,
    int N)
{
    __shared__ unsigned short wt[64 * 256];   // 32 KB: wt[col][k] (swizzled)
    __shared__ unsigned short xs[128 * 64];   // 16 KB: xs[row][k-in-chunk] (swizzled)

    const int tid  = threadIdx.x;
    const int lane = tid & 63;
    const int w    = tid >> 6;                  // wave 0..7
    const int cg   = lane & 15;                 // col-in-tile / row-in-tile
    const int g    = lane >> 4;                 // quad group 0..3
    const long long row0 = (long long)blockIdx.x * GEMM_BM;

    // ---- stage W transposed (once): thread -> col c = tid>>3, k0 = (tid&7)*32
    {
        const int c  = tid >> 3;
        const int k0 = (tid & 7) * 32;
        unsigned short tmp[32];
#pragma unroll
        for (int j = 0; j < 32; ++j)
            tmp[j] = f2bf(W[(k0 + j) * 64 + c]);
        const int xorv = (c & 7) << 4;
        char* wb = (char*)wt + c * 512;
#pragma unroll
        for (int q = 0; q < 4; ++q) {
            int kbyte = (k0 + q * 8) * 2;
            *(u16x8*)(wb + (kbyte ^ xorv)) = *(u16x8*)&tmp[q * 8];
        }
    }

    f32x4 acc[4];
#pragma unroll
    for (int ct = 0; ct < 4; ++ct) acc[ct] = (f32x4){0.f, 0.f, 0.f, 0.f};

    // A-frag LDS address (constant across chunks)
    const int arow  = w * 16 + cg;
    const int axor  = (arow & 7) << 4;
    char* const abase = (char*)xs + arow * 128;

    for (int kc = 0; kc < 256; kc += 64) {
        __syncthreads();   // previous chunk's reads done (and W writes on iter 0)
        // ---- stage x chunk: 128 rows x 64 k; thread -> row tid>>2, kseg (tid&3)*16
        {
            const int r  = tid >> 2;
            const int ks = (tid & 3) * 16;
            long long gr = row0 + r;
            if (gr > (long long)N - 1) gr = (long long)N - 1;
            const float* xp = &x[gr * 256 + kc + ks];
            float4 v0 = *(const float4*)&xp[0];
            float4 v1 = *(const float4*)&xp[4];
            float4 v2 = *(const float4*)&xp[8];
            float4 v3 = *(const float4*)&xp[12];
            unsigned short tmp[16];
            tmp[0]=f2bf(v0.x); tmp[1]=f2bf(v0.y); tmp[2]=f2bf(v0.z); tmp[3]=f2bf(v0.w);
            tmp[4]=f2bf(v1.x); tmp[5]=f2bf(v1.y); tmp[6]=f2bf(v1.z); tmp[7]=f2bf(v1.w);
            tmp[8]=f2bf(v2.x); tmp[9]=f2bf(v2.y); tmp[10]=f2bf(v2.z); tmp[11]=f2bf(v2.w);
            tmp[12]=f2bf(v3.x); tmp[13]=f2bf(v3.y); tmp[14]=f2bf(v3.z); tmp[15]=f2bf(v3.w);
            const int xorv = (r & 7) << 4;
            char* xb = (char*)xs + r * 128;
            *(u16x8*)(xb + ((ks * 2) ^ xorv))      = *(u16x8*)&tmp[0];
            *(u16x8*)(xb + ((ks * 2 + 16) ^ xorv)) = *(u16x8*)&tmp[8];
        }
        __syncthreads();

#pragma unroll
        for (int s = 0; s < 2; ++s) {
            bf16x8 af = *(bf16x8*)(abase + (((s * 32 + g * 8) * 2) ^ axor));
#pragma unroll
            for (int ct = 0; ct < 4; ++ct) {
                const int col = ct * 16 + cg;
                const int kbyte = (kc + s * 32) * 2 + g * 16;
                bf16x8 bf_ = *(bf16x8*)((char*)wt + col * 512 + (kbyte ^ ((col & 7) << 4)));
                acc[ct] = __builtin_amdgcn_mfma_f32_16x16x32_bf16(af, bf_, acc[ct], 0, 0, 0);
            }
        }
    }

    // ---- epilogue: store bf16 h; f1/f2 from fp32 accumulators
    float a1v[4], a2v[4];
#pragma unroll
    for (int ct = 0; ct < 4; ++ct) {
        a1v[ct] = a1[ct * 16 + cg];
        a2v[ct] = a2[ct * 16 + cg];
    }
    const float b1 = a1b[0], b2 = a2b[0];

#pragma unroll
    for (int r = 0; r < 4; ++r) {
        const long long row = row0 + w * 16 + g * 4 + r;
        const bool ok = (row < N);
        float p1 = 0.f, p2 = 0.f;
#pragma unroll
        for (int ct = 0; ct < 4; ++ct) {
            float hv = acc[ct][r];
            if (ok) hb[row * 64 + ct * 16 + cg] = f2bf(hv);
            p1 = fmaf(hv, a1v[ct], p1);
            p2 = fmaf(hv, a2v[ct], p2);
        }
#pragma unroll
        for (int d = 8; d > 0; d >>= 1) {
            p1 += __shfl_xor(p1, d);
            p2 += __shfl_xor(p2, d);
        }
        if (ok && cg == 0) {
            f1[row] = p1 + b1;
            f2[row] = p2 + b2;
        }
    }
}

// ---------------------------------------------------------------------------
// Phase A: per-block LDS bucket histogram -> ONE global atomicAdd per bucket.
// ---------------------------------------------------------------------------
__global__ __launch_bounds__(512) void gat_hist(
    const int* __restrict__ src, int* __restrict__ bcnt, int E, int nbuck)
{
    __shared__ int hist[512];
    const int tid = threadIdx.x;
    hist[tid] = 0;
    __syncthreads();
    const long long base = (long long)blockIdx.x * BW_CHUNK;
#pragma unroll 4
    for (int k = 0; k < BW_CHUNK / 512; ++k) {
        long long i = base + k * 512 + tid;
        if (i < E) atomicAdd(&hist[src[i] >> BUCKET_SHIFT], 1);
    }
    __syncthreads();
    if (tid < nbuck && hist[tid]) atomicAdd(&bcnt[tid], hist[tid]);
}

// ---------------------------------------------------------------------------
// Single-block exclusive scan of bucket totals -> bbase[0..nbuck], cursor[].
// ---------------------------------------------------------------------------
__global__ __launch_bounds__(512) void gat_bscan(
    const int* __restrict__ bcnt, int* __restrict__ bbase,
    int* __restrict__ cursor, int nbuck, int E)
{
    __shared__ int s[512];
    const int t = threadIdx.x;
    int v = (t < nbuck) ? bcnt[t] : 0;
    s[t] = v;
    __syncthreads();
    for (int off = 1; off < 512; off <<= 1) {
        int u = (t >= off) ? s[t - off] : 0;
        __syncthreads();
        s[t] += u;
        __syncthreads();
    }
    if (t < nbuck) {
        int ex = s[t] - v;
        bbase[t]  = ex;
        cursor[t] = ex;
    }
    if (t == 0) bbase[nbuck] = E;
}

// ---------------------------------------------------------------------------
// Phase B: LDS counting-sort block pass (radix-sort style).
// pass 1: LDS bucket hist over src; local exclusive scan; reserve contiguous
//         per-bucket global ranges (one atomic per bucket).
// pass 2: re-read edges, place payload {(dst<<8)|src_local, adj} into LDS buf
//         at bucket-sorted local position (LDS atomic -> LDS write; no global
//         scatter in the dependent chain).
// pass 3: per-bucket runs written to global as contiguous wave-cooperative
//         stores -> each cache line filled once, single writeback.
// ---------------------------------------------------------------------------
__global__ __launch_bounds__(512) void gat_binwrite(
    const int* __restrict__ src, const int* __restrict__ dst,
    const float* __restrict__ adj,
    int* __restrict__ cursor, int2* __restrict__ bin, int E, int nbuck)
{
    __shared__ int2 buf[BW_CHUNK];    // 64 KB: bucket-sorted payloads
    __shared__ int hist[512];         // counts -> running local cursors -> run ends
    __shared__ int lbase[512];        // local exclusive base per bucket
    __shared__ int gbase[512];        // reserved global base per bucket
    const int tid = threadIdx.x;
    hist[tid] = 0;
    __syncthreads();

    const long long base = (long long)blockIdx.x * BW_CHUNK;
    // pass 1: histogram
#pragma unroll 4
    for (int k = 0; k < BW_CHUNK / 512; ++k) {
        long long i = base + k * 512 + tid;
        if (i < E) atomicAdd(&hist[src[i] >> BUCKET_SHIFT], 1);
    }
    __syncthreads();

    // local inclusive scan (Hillis-Steele over 512)
    const int cnt = hist[tid];
    lbase[tid] = cnt;
    __syncthreads();
    for (int off = 1; off < 512; off <<= 1) {
        int u = (tid >= off) ? lbase[tid - off] : 0;
        __syncthreads();
        lbase[tid] += u;
        __syncthreads();
    }
    const int excl = lbase[tid] - cnt;   // own-entry only: no cross-thread hazard
    lbase[tid] = excl;
    // reserve global range for this block's portion of each bucket
    if (tid < nbuck) gbase[tid] = cnt ? atomicAdd(&cursor[tid], cnt) : 0;
    hist[tid] = excl;                    // reuse as running local cursor
    __syncthreads();

    // pass 2: sort into LDS
#pragma unroll 4
    for (int k = 0; k < BW_CHUNK / 512; ++k) {
        long long i = base + k * 512 + tid;
        if (i < E) {
            int s = src[i], d = dst[i];
            float a = adj[i];
            int lp = atomicAdd(&hist[s >> BUCKET_SHIFT], 1);
            buf[lp] = make_int2((d << BUCKET_SHIFT) | (s & 255), __float_as_int(a));
        }
    }
    __syncthreads();

    // pass 3: run-contiguous global writes (wave w handles buckets w, w+8, ...)
    const int wv = tid >> 6, ln = tid & 63;
    for (int r = wv; r < nbuck; r += 8) {
        const int lb = lbase[r];
        const int len = hist[r] - lb;    // final cursor - base = count
        const int gb = gbase[r];
        for (int j = ln; j < len; j += 64)
            bin[gb + j] = buf[lb + j];
    }
}

// ---------------------------------------------------------------------------
// Phase C: one block per bucket. Preload f1 for the bucket's 256 nodes (LDS);
// local degree hist + scan writes row_start; then in-place scatter computing
// e = a*f1[s] + a*f2[d] (f2 gather = independent-iteration MLP), leaky, exp,
// -> csr {dst, p}.
// ---------------------------------------------------------------------------
__global__ __launch_bounds__(512) void gat_bucket_scatter(
    const int* __restrict__ bbase, int* __restrict__ row_start,
    const float* __restrict__ f1, const float* __restrict__ f2,
    int2* __restrict__ csr, int N, int E)
{
    __shared__ int2 buf[PHC_CAP];
    __shared__ int hist[256];     // degree hist, later reused as cursors
    __shared__ int sc[256];       // inclusive scan
    __shared__ float f1s[256];    // bucket-local f1
    const int tid = threadIdx.x;
    const int b = blockIdx.x;
    const int n0 = b << BUCKET_SHIFT;
    int n1 = n0 + 256; if (n1 > N) n1 = N;
    const int nn = n1 - n0;

    const int bstart = bbase[b];
    const int bend   = bbase[b + 1];
    int cntb = bend - bstart;
    if (cntb > PHC_CAP) cntb = PHC_CAP;           // statistically unreachable guard

    if (tid < 256) {
        hist[tid] = 0;
        f1s[tid] = (tid < nn) ? f1[n0 + tid] : 0.f;
    }
    for (int i = tid; i < cntb; i += 512) buf[i] = csr[bstart + i];
    __syncthreads();

    for (int i = tid; i < cntb; i += 512)
        atomicAdd(&hist[buf[i].x & 255], 1);
    __syncthreads();

    int v = (tid < 256) ? hist[tid] : 0;
    if (tid < 256) sc[tid] = v;
    __syncthreads();
    for (int off = 1; off < 256; off <<= 1) {
        int u = (tid < 256 && tid >= off) ? sc[tid - off] : 0;
        __syncthreads();
        if (tid < 256) sc[tid] += u;
        __syncthreads();
    }
    if (tid < 256) {
        int ex = bstart + sc[tid] - v;   // exclusive prefix + bucket base
        hist[tid] = ex;                  // reuse as cursor
        if (tid < nn) row_start[n0 + tid] = ex;
    }
    if (b == gridDim.x - 1 && tid == 0) row_start[N] = E;
    __syncthreads();

    for (int i = tid; i < cntb; i += 512) {
        int2 ev = buf[i];
        int sl = ev.x & 255;
        int dv = ev.x >> BUCKET_SHIFT;
        float a = __int_as_float(ev.y);
        float e = a * f1s[sl] + a * f2[dv];
        e = (e > 0.f) ? e : ALPHA * e;
        float p = __expf(e);
        int pos = atomicAdd(&hist[sl], 1);
        csr[pos] = make_int2(dv, __float_as_int(p));
    }
}

// ---------------------------------------------------------------------------
// Fallback kernels + generic scan (only used if bucket limits are exceeded).
// ---------------------------------------------------------------------------
__global__ void gat_deg(const int* __restrict__ src, int* __restrict__ deg, int E)
{
    int i = blockIdx.x * blockDim.x + threadIdx.x;
    if (i < E) atomicAdd(&deg[src[i]], 1);
}

__global__ void gat_scanA(const int* __restrict__ in, int* __restrict__ bsums, int n)
{
    __shared__ int s[256];
    int t = threadIdx.x;
    int i = blockIdx.x * 256 + t;
    s[t] = (i < n) ? in[i] : 0;
    __syncthreads();
    for (int off = 128; off > 0; off >>= 1) {
        if (t < off) s[t] += s[t + off];
        __syncthreads();
    }
    if (t == 0) bsums[blockIdx.x] = s[0];
}

__global__ void gat_scanB(const int* __restrict__ bsums, int* __restrict__ bofs, int nb)
{
    __shared__ int s[512];
    int t = threadIdx.x;
    int v = (t < nb) ? bsums[t] : 0;
    s[t] = v;
    __syncthreads();
    for (int off = 1; off < 512; off <<= 1) {
        int u = (t >= off) ? s[t - off] : 0;
        __syncthreads();
        s[t] += u;
        __syncthreads();
    }
    if (t < nb) bofs[t] = s[t] - v;   // exclusive
}

__global__ void gat_scanC(const int* __restrict__ in, const int* __restrict__ bofs,
                          int* __restrict__ out, int* __restrict__ cursor, int n)
{
    __shared__ int s[256];
    int t = threadIdx.x;
    int i = blockIdx.x * 256 + t;
    int v = (i < n) ? in[i] : 0;
    s[t] = v;
    __syncthreads();
    for (int off = 1; off < 256; off <<= 1) {
        int u = (t >= off) ? s[t - off] : 0;
        __syncthreads();
        s[t] += u;
        __syncthreads();
    }
    if (i < n) {
        int excl = bofs[blockIdx.x] + s[t] - v;
        out[i] = excl;
        if (cursor) cursor[i] = excl;
        if (i == n - 1) out[n] = excl + v;
    }
}

__global__ void gat_scatter(const int* __restrict__ src, const int* __restrict__ dst,
                            const float* __restrict__ adj,
                            const float* __restrict__ f1, const float* __restrict__ f2,
                            int* __restrict__ cursor, int2* __restrict__ csr, int E)
{
    int i = blockIdx.x * blockDim.x + threadIdx.x;
    if (i >= E) return;
    int sv = src[i], dv = dst[i];
    float a = adj[i];
    float e = a * f1[sv] + a * f2[dv];
    e = (e > 0.f) ? e : ALPHA * e;
    float p = __expf(e);
    int pos = atomicAdd(&cursor[sv], 1);
    csr[pos] = make_int2(dv, __float_as_int(p));
}

// ---------------------------------------------------------------------------
// Per-node weighted gather over bf16 h. One wave per node; 4 edges per
// iteration slot (eg = lane>>4) x 16 feature quads (cg = lane&15).
// Unroll x2: two independent (bc, hv) pairs in flight per wave. LDS strip
// padding always carries p=0/boff=0, so reading past cnt is safe.
// ---------------------------------------------------------------------------
__global__ __launch_bounds__(256) void gat_gather(
    const int* __restrict__ row_start, const int2* __restrict__ csr,
    const unsigned short* __restrict__ hb,
    const float* __restrict__ bias, float* __restrict__ out, int N)
{
    __shared__ float2 sh[4][64];
    const int lane = threadIdx.x & 63;
    const int wid  = threadIdx.x >> 6;
    const int node = blockIdx.x * 4 + wid;
    if (node >= N) return;

    const int cg = lane & 15;      // feature quad: cols cg*4 .. cg*4+3
    const int eg = lane >> 4;      // edge slot 0..3

    const int rs = row_start[node];
    const int re = row_start[node + 1];
    float* op = out + (long long)node * 64;
    const float4 bl4 = *(const float4*)&bias[cg * 4];

    if (re <= rs) {
        if (lane < 16) *(float4*)&op[cg * 4] = bl4;
        return;
    }

    const char* hbase = (const char*)hb + (size_t)cg * 8;

    float acc0 = 0.f, acc1 = 0.f, acc2 = 0.f, acc3 = 0.f, ssum = 0.f;
    for (int base = rs; base < re; base += 64) {
        int idx = base + lane;
        float p = 0.f;
        int boff = 0;
        if (idx < re) {
            int2 de = csr[idx];
            boff = de.x << 7;            // dst * 128 bytes (bf16 row)
            p = __int_as_float(de.y);
        }
        ssum += p;
        sh[wid][lane] = make_float2(p, __int_as_float(boff));  // padding: p=0
        __builtin_amdgcn_wave_barrier();
        __threadfence_block();           // order LDS write -> cross-lane reads
        int cnt = re - base; if (cnt > 64) cnt = 64;
        for (int j = 0; j < cnt; j += 8) {
            float2 bcA = sh[wid][j + eg];
            float2 bcB = sh[wid][j + 4 + eg];        // may be padding: p=0, safe
            uint2 hvA = *(const uint2*)(hbase + __float_as_int(bcA.y));
            uint2 hvB = *(const uint2*)(hbase + __float_as_int(bcB.y));
            float pA = bcA.x, pB = bcB.x;
            acc0 = fmaf(pA, __uint_as_float(hvA.x << 16), acc0);
            acc1 = fmaf(pA, __uint_as_float(hvA.x & 0xFFFF0000u), acc1);
            acc2 = fmaf(pA, __uint_as_float(hvA.y << 16), acc2);
            acc3 = fmaf(pA, __uint_as_float(hvA.y & 0xFFFF0000u), acc3);
            acc0 = fmaf(pB, __uint_as_float(hvB.x << 16), acc0);
            acc1 = fmaf(pB, __uint_as_float(hvB.x & 0xFFFF0000u), acc1);
            acc2 = fmaf(pB, __uint_as_float(hvB.y << 16), acc2);
            acc3 = fmaf(pB, __uint_as_float(hvB.y & 0xFFFF0000u), acc3);
        }
        __builtin_amdgcn_wave_barrier();
        __threadfence_block();           // keep next write after these reads
    }
#pragma unroll
    for (int d = 32; d > 0; d >>= 1) ssum += __shfl_xor(ssum, d);
    acc0 += __shfl_xor(acc0, 16); acc0 += __shfl_xor(acc0, 32);
    acc1 += __shfl_xor(acc1, 16); acc1 += __shfl_xor(acc1, 32);
    acc2 += __shfl_xor(acc2, 16); acc2 += __shfl_xor(acc2, 32);
    acc3 += __shfl_xor(acc3, 16); acc3 += __shfl_xor(acc3, 32);

    if (lane < 16) {
        const float inv = 1.f / ssum;    // ssum > 0 (p = exp > 0)
        float4 o;
        o.x = fmaf(acc0, inv, bl4.x);
        o.y = fmaf(acc1, inv, bl4.y);
        o.z = fmaf(acc2, inv, bl4.z);
        o.w = fmaf(acc3, inv, bl4.w);
        *(float4*)&op[cg * 4] = o;
    }
}

// ---------------------------------------------------------------------------
extern "C" void kernel_launch(void* const* d_in, const int* in_sizes, int n_in,
                              void* d_out, int out_size, void* d_ws, size_t ws_size,
                              hipStream_t stream)
{
    const float* x    = (const float*)d_in[0];
    const int*   esrc = (const int*)d_in[1];
    const int*   edst = (const int*)d_in[2];
    const float* adj  = (const float*)d_in[3];
    const float* W    = (const float*)d_in[4];
    const float* a1   = (const float*)d_in[5];
    const float* a1b  = (const float*)d_in[6];
    const float* a2   = (const float*)d_in[7];
    const float* a2b  = (const float*)d_in[8];
    const float* bias = (const float*)d_in[9];
    float* out = (float*)d_out;

    const int N = in_sizes[0] / 256;
    const int E = in_sizes[1];

    const int nbuck = (N + 255) >> BUCKET_SHIFT;
    const int nblk  = (E + BW_CHUNK - 1) / BW_CHUNK;

    // workspace carve-up
    char* p = (char*)d_ws;
    unsigned short* hbuf = (unsigned short*)p;  p += (size_t)N * 64 * 2;
    p = (char*)(((uintptr_t)p + 255) & ~(uintptr_t)255);
    float* f1  = (float*)p;  p += (size_t)N * 4;
    float* f2  = (float*)p;  p += (size_t)N * 4;
    int* deg   = (int*)p;    p += (size_t)N * 4;
    int* row_start = (int*)p; p += (size_t)(N + 1) * 4;
    p = (char*)(((uintptr_t)p + 255) & ~(uintptr_t)255);
    int* cursor = (int*)p;   p += (size_t)N * 4;       // binned: nbuck entries used
    int* bsums  = (int*)p;   p += 512 * 4;
    int* bofs   = (int*)p;   p += 512 * 4;
    p = (char*)(((uintptr_t)p + 255) & ~(uintptr_t)255);
    int* bcnt  = (int*)p;    p += 512 * 4;
    int* bbase = (int*)p;    p += 520 * 4;
    p = (char*)(((uintptr_t)p + 255) & ~(uintptr_t)255);
    int2* csr  = (int2*)p;   p += (size_t)E * 8;
    const size_t required = (size_t)(p - (char*)d_ws);

    const bool binned = (nbuck <= 512) && (required <= ws_size);

    const int nbN = (N + 255) / 256;
    const int gemm_blocks = (N + GEMM_BM - 1) / GEMM_BM;

    hipLaunchKernelGGL(gat_gemm, dim3(gemm_blocks), dim3(512), 0, stream,
                       x, W, a1, a1b, a2, a2b, hbuf, f1, f2, N);

    if (binned) {
        hipMemsetAsync(bcnt, 0, 512 * 4, stream);
        hipLaunchKernelGGL(gat_hist, dim3(nblk), dim3(512), 0, stream,
                           esrc, bcnt, E, nbuck);
        hipLaunchKernelGGL(gat_bscan, dim3(1), dim3(512), 0, stream,
                           bcnt, bbase, cursor, nbuck, E);
        hipLaunchKernelGGL(gat_binwrite, dim3(nblk), dim3(512), 0, stream,
                           esrc, edst, adj, cursor, csr, E, nbuck);
        hipLaunchKernelGGL(gat_bucket_scatter, dim3(nbuck), dim3(512), 0, stream,
                           bbase, row_start, f1, f2, csr, N, E);
    } else {
        hipMemsetAsync(deg, 0, (size_t)N * 4, stream);
        hipLaunchKernelGGL(gat_deg, dim3((E + 255) / 256), dim3(256), 0, stream,
                           esrc, deg, E);
        hipLaunchKernelGGL(gat_scanA, dim3(nbN), dim3(256), 0, stream, deg, bsums, N);
        hipLaunchKernelGGL(gat_scanB, dim3(1), dim3(512), 0, stream, bsums, bofs, nbN);
        hipLaunchKernelGGL(gat_scanC, dim3(nbN), dim3(256), 0, stream,
                           deg, bofs, row_start, cursor, N);
        hipLaunchKernelGGL(gat_scatter, dim3((E + 255) / 256), dim3(256), 0, stream,
                           esrc, edst, adj, f1, f2, cursor, csr, E);
    }

    hipLaunchKernelGGL(gat_gather, dim3((N + 3) / 4), dim3(256), 0, stream,
                       row_start, csr, hbuf, bias, out, N);
}

// Round 14
// 167.676 us; speedup vs baseline: 1.4412x; 1.0795x over previous
//
#include <hip/hip_runtime.h>
#include <math.h>
#include <stdint.h>

#define ALPHA 0.2f
#define HIST_CHUNK 8192           // edges per hist block (16 x 512)
#define BW_CHUNK 5120             // edges per binwrite block (10 x 512) - LDS fit
#define BUCKET_SHIFT 8            // 256 nodes per bucket
#define PHC_CAP 12288             // bucket LDS capacity; mean ~8192, +45 sigma
#define SMEM_BYTES 49152          // union: gemm 48K | binwrite 40K buf + 6K aux

typedef __attribute__((ext_vector_type(8))) short bf16x8;
typedef __attribute__((ext_vector_type(4))) float f32x4;
typedef __attribute__((ext_vector_type(8))) unsigned short u16x8;

// bf16 round-to-nearest-even
__device__ __forceinline__ unsigned short f2bf(float f)
{
    unsigned int u = __float_as_uint(f);
    unsigned int r = (u + 0x7FFFu + ((u >> 16) & 1u)) >> 16;
    return (unsigned short)r;
}

// ---------------------------------------------------------------------------
// GEMM body: h = x @ W -> hb (bf16), f1/f2 from fp32 accumulators.
// 512 threads = 8 waves; tile 128 rows x 64 cols; BK=64. smem: wt 32K + xs 16K.
// ---------------------------------------------------------------------------
#define GEMM_BM 128

__device__ __forceinline__ void gemm_body(
    char* smem,
    const float* __restrict__ x, const float* __restrict__ W,
    const float* __restrict__ a1, const float* __restrict__ a1b,
    const float* __restrict__ a2, const float* __restrict__ a2b,
    unsigned short* __restrict__ hb, float* __restrict__ f1, float* __restrict__ f2,
    int N, int bid)
{
    unsigned short* wt = (unsigned short*)smem;            // 32 KB: wt[col][k]
    unsigned short* xs = (unsigned short*)(smem + 32768);  // 16 KB: xs[row][kchunk]

    const int tid  = threadIdx.x;
    const int lane = tid & 63;
    const int w    = tid >> 6;
    const int cg   = lane & 15;
    const int g    = lane >> 4;
    const long long row0 = (long long)bid * GEMM_BM;

    // stage W transposed (once): col c = tid>>3, k0 = (tid&7)*32
    {
        const int c  = tid >> 3;
        const int k0 = (tid & 7) * 32;
        unsigned short tmp[32];
#pragma unroll
        for (int j = 0; j < 32; ++j)
            tmp[j] = f2bf(W[(k0 + j) * 64 + c]);
        const int xorv = (c & 7) << 4;
        char* wb = (char*)wt + c * 512;
#pragma unroll
        for (int q = 0; q < 4; ++q) {
            int kbyte = (k0 + q * 8) * 2;
            *(u16x8*)(wb + (kbyte ^ xorv)) = *(u16x8*)&tmp[q * 8];
        }
    }

    f32x4 acc[4];
#pragma unroll
    for (int ct = 0; ct < 4; ++ct) acc[ct] = (f32x4){0.f, 0.f, 0.f, 0.f};

    const int arow  = w * 16 + cg;
    const int axor  = (arow & 7) << 4;
    char* const abase = (char*)xs + arow * 128;

    for (int kc = 0; kc < 256; kc += 64) {
        __syncthreads();
        {
            const int r  = tid >> 2;
            const int ks = (tid & 3) * 16;
            long long gr = row0 + r;
            if (gr > (long long)N - 1) gr = (long long)N - 1;
            const float* xp = &x[gr * 256 + kc + ks];
            float4 v0 = *(const float4*)&xp[0];
            float4 v1 = *(const float4*)&xp[4];
            float4 v2 = *(const float4*)&xp[8];
            float4 v3 = *(const float4*)&xp[12];
            unsigned short tmp[16];
            tmp[0]=f2bf(v0.x); tmp[1]=f2bf(v0.y); tmp[2]=f2bf(v0.z); tmp[3]=f2bf(v0.w);
            tmp[4]=f2bf(v1.x); tmp[5]=f2bf(v1.y); tmp[6]=f2bf(v1.z); tmp[7]=f2bf(v1.w);
            tmp[8]=f2bf(v2.x); tmp[9]=f2bf(v2.y); tmp[10]=f2bf(v2.z); tmp[11]=f2bf(v2.w);
            tmp[12]=f2bf(v3.x); tmp[13]=f2bf(v3.y); tmp[14]=f2bf(v3.z); tmp[15]=f2bf(v3.w);
            const int xorv = (r & 7) << 4;
            char* xb = (char*)xs + r * 128;
            *(u16x8*)(xb + ((ks * 2) ^ xorv))      = *(u16x8*)&tmp[0];
            *(u16x8*)(xb + ((ks * 2 + 16) ^ xorv)) = *(u16x8*)&tmp[8];
        }
        __syncthreads();

#pragma unroll
        for (int s = 0; s < 2; ++s) {
            bf16x8 af = *(bf16x8*)(abase + (((s * 32 + g * 8) * 2) ^ axor));
#pragma unroll
            for (int ct = 0; ct < 4; ++ct) {
                const int col = ct * 16 + cg;
                const int kbyte = (kc + s * 32) * 2 + g * 16;
                bf16x8 bf_ = *(bf16x8*)((char*)wt + col * 512 + (kbyte ^ ((col & 7) << 4)));
                acc[ct] = __builtin_amdgcn_mfma_f32_16x16x32_bf16(af, bf_, acc[ct], 0, 0, 0);
            }
        }
    }

    float a1v[4], a2v[4];
#pragma unroll
    for (int ct = 0; ct < 4; ++ct) {
        a1v[ct] = a1[ct * 16 + cg];
        a2v[ct] = a2[ct * 16 + cg];
    }
    const float b1 = a1b[0], b2 = a2b[0];

#pragma unroll
    for (int r = 0; r < 4; ++r) {
        const long long row = row0 + w * 16 + g * 4 + r;
        const bool ok = (row < N);
        float p1 = 0.f, p2 = 0.f;
#pragma unroll
        for (int ct = 0; ct < 4; ++ct) {
            float hv = acc[ct][r];
            if (ok) hb[row * 64 + ct * 16 + cg] = f2bf(hv);
            p1 = fmaf(hv, a1v[ct], p1);
            p2 = fmaf(hv, a2v[ct], p2);
        }
#pragma unroll
        for (int d = 8; d > 0; d >>= 1) {
            p1 += __shfl_xor(p1, d);
            p2 += __shfl_xor(p2, d);
        }
        if (ok && cg == 0) {
            f1[row] = p1 + b1;
            f2[row] = p2 + b2;
        }
    }
}

// ---------------------------------------------------------------------------
// Binwrite body: LDS counting-sort block pass. hist -> local scan -> global
// range reservation -> sort payloads {(dst<<8)|src_local, adj} into LDS ->
// run-contiguous global writes.
// ---------------------------------------------------------------------------
__device__ __forceinline__ void binwrite_body(
    char* smem,
    const int* __restrict__ src, const int* __restrict__ dst,
    const float* __restrict__ adj,
    int* __restrict__ cursor, int2* __restrict__ bin, int E, int nbuck, int bid)
{
    int2* buf  = (int2*)smem;                        // 40 KB
    int* hist  = (int*)(smem + BW_CHUNK * 8);        // 2 KB
    int* lbase = hist + 512;                         // 2 KB
    int* gbase = lbase + 512;                        // 2 KB
    const int tid = threadIdx.x;
    hist[tid] = 0;
    __syncthreads();

    const long long base = (long long)bid * BW_CHUNK;
#pragma unroll 2
    for (int k = 0; k < BW_CHUNK / 512; ++k) {
        long long i = base + k * 512 + tid;
        if (i < E) atomicAdd(&hist[src[i] >> BUCKET_SHIFT], 1);
    }
    __syncthreads();

    const int cnt = hist[tid];
    lbase[tid] = cnt;
    __syncthreads();
    for (int off = 1; off < 512; off <<= 1) {
        int u = (tid >= off) ? lbase[tid - off] : 0;
        __syncthreads();
        lbase[tid] += u;
        __syncthreads();
    }
    const int excl = lbase[tid] - cnt;
    lbase[tid] = excl;
    if (tid < nbuck) gbase[tid] = cnt ? atomicAdd(&cursor[tid], cnt) : 0;
    hist[tid] = excl;                    // running local cursor
    __syncthreads();

#pragma unroll 2
    for (int k = 0; k < BW_CHUNK / 512; ++k) {
        long long i = base + k * 512 + tid;
        if (i < E) {
            int s = src[i], d = dst[i];
            float a = adj[i];
            int lp = atomicAdd(&hist[s >> BUCKET_SHIFT], 1);
            buf[lp] = make_int2((d << BUCKET_SHIFT) | (s & 255), __float_as_int(a));
        }
    }
    __syncthreads();

    const int wv = tid >> 6, ln = tid & 63;
    for (int r = wv; r < nbuck; r += 8) {
        const int lb = lbase[r];
        const int len = hist[r] - lb;
        const int gb = gbase[r];
        for (int j = ln; j < len; j += 64)
            bin[gb + j] = buf[lb + j];
    }
}

// ---------------------------------------------------------------------------
// FUSED kernel: blocks [0, nbinblk) run binwrite; the rest run gemm tiles.
// The two roles touch disjoint data; LDS is a 48 KB union.
// ---------------------------------------------------------------------------
__global__ __launch_bounds__(512) void gat_gemm_binw(
    const float* __restrict__ x, const float* __restrict__ W,
    const float* __restrict__ a1, const float* __restrict__ a1b,
    const float* __restrict__ a2, const float* __restrict__ a2b,
    unsigned short* __restrict__ hb, float* __restrict__ f1, float* __restrict__ f2,
    int N,
    const int* __restrict__ src, const int* __restrict__ dst,
    const float* __restrict__ adj,
    int* __restrict__ cursor, int2* __restrict__ bin, int E, int nbuck, int nbinblk)
{
    __shared__ __align__(16) char smem[SMEM_BYTES];
    if ((int)blockIdx.x < nbinblk)
        binwrite_body(smem, src, dst, adj, cursor, bin, E, nbuck, blockIdx.x);
    else
        gemm_body(smem, x, W, a1, a1b, a2, a2b, hb, f1, f2, N, blockIdx.x - nbinblk);
}

// standalone gemm (fallback path)
__global__ __launch_bounds__(512) void gat_gemm(
    const float* __restrict__ x, const float* __restrict__ W,
    const float* __restrict__ a1, const float* __restrict__ a1b,
    const float* __restrict__ a2, const float* __restrict__ a2b,
    unsigned short* __restrict__ hb, float* __restrict__ f1, float* __restrict__ f2,
    int N)
{
    __shared__ __align__(16) char smem[SMEM_BYTES];
    gemm_body(smem, x, W, a1, a1b, a2, a2b, hb, f1, f2, N, blockIdx.x);
}

// ---------------------------------------------------------------------------
// Phase A: per-block LDS bucket histogram -> ONE global atomicAdd per bucket.
// ---------------------------------------------------------------------------
__global__ __launch_bounds__(512) void gat_hist(
    const int* __restrict__ src, int* __restrict__ bcnt, int E, int nbuck)
{
    __shared__ int hist[512];
    const int tid = threadIdx.x;
    hist[tid] = 0;
    __syncthreads();
    const long long base = (long long)blockIdx.x * HIST_CHUNK;
#pragma unroll 4
    for (int k = 0; k < HIST_CHUNK / 512; ++k) {
        long long i = base + k * 512 + tid;
        if (i < E) atomicAdd(&hist[src[i] >> BUCKET_SHIFT], 1);
    }
    __syncthreads();
    if (tid < nbuck && hist[tid]) atomicAdd(&bcnt[tid], hist[tid]);
}

// ---------------------------------------------------------------------------
// Single-block exclusive scan of bucket totals -> bbase[0..nbuck], cursor[].
// ---------------------------------------------------------------------------
__global__ __launch_bounds__(512) void gat_bscan(
    const int* __restrict__ bcnt, int* __restrict__ bbase,
    int* __restrict__ cursor, int nbuck, int E)
{
    __shared__ int s[512];
    const int t = threadIdx.x;
    int v = (t < nbuck) ? bcnt[t] : 0;
    s[t] = v;
    __syncthreads();
    for (int off = 1; off < 512; off <<= 1) {
        int u = (t >= off) ? s[t - off] : 0;
        __syncthreads();
        s[t] += u;
        __syncthreads();
    }
    if (t < nbuck) {
        int ex = s[t] - v;
        bbase[t]  = ex;
        cursor[t] = ex;
    }
    if (t == 0) bbase[nbuck] = E;
}

// ---------------------------------------------------------------------------
// Phase C: one block per bucket. Preload f1 (bucket-local LDS); degree hist +
// scan writes row_start; in-place scatter computing e = a*f1[s] + a*f2[d],
// leaky, exp -> csr {dst, p}.
// ---------------------------------------------------------------------------
__global__ __launch_bounds__(512) void gat_bucket_scatter(
    const int* __restrict__ bbase, int* __restrict__ row_start,
    const float* __restrict__ f1, const float* __restrict__ f2,
    int2* __restrict__ csr, int N, int E)
{
    __shared__ int2 buf[PHC_CAP];
    __shared__ int hist[256];
    __shared__ int sc[256];
    __shared__ float f1s[256];
    const int tid = threadIdx.x;
    const int b = blockIdx.x;
    const int n0 = b << BUCKET_SHIFT;
    int n1 = n0 + 256; if (n1 > N) n1 = N;
    const int nn = n1 - n0;

    const int bstart = bbase[b];
    const int bend   = bbase[b + 1];
    int cntb = bend - bstart;
    if (cntb > PHC_CAP) cntb = PHC_CAP;

    if (tid < 256) {
        hist[tid] = 0;
        f1s[tid] = (tid < nn) ? f1[n0 + tid] : 0.f;
    }
    for (int i = tid; i < cntb; i += 512) buf[i] = csr[bstart + i];
    __syncthreads();

    for (int i = tid; i < cntb; i += 512)
        atomicAdd(&hist[buf[i].x & 255], 1);
    __syncthreads();

    int v = (tid < 256) ? hist[tid] : 0;
    if (tid < 256) sc[tid] = v;
    __syncthreads();
    for (int off = 1; off < 256; off <<= 1) {
        int u = (tid < 256 && tid >= off) ? sc[tid - off] : 0;
        __syncthreads();
        if (tid < 256) sc[tid] += u;
        __syncthreads();
    }
    if (tid < 256) {
        int ex = bstart + sc[tid] - v;
        hist[tid] = ex;
        if (tid < nn) row_start[n0 + tid] = ex;
    }
    if (b == gridDim.x - 1 && tid == 0) row_start[N] = E;
    __syncthreads();

    for (int i = tid; i < cntb; i += 512) {
        int2 ev = buf[i];
        int sl = ev.x & 255;
        int dv = ev.x >> BUCKET_SHIFT;
        float a = __int_as_float(ev.y);
        float e = a * f1s[sl] + a * f2[dv];
        e = (e > 0.f) ? e : ALPHA * e;
        float p = __expf(e);
        int pos = atomicAdd(&hist[sl], 1);
        csr[pos] = make_int2(dv, __float_as_int(p));
    }
}

// ---------------------------------------------------------------------------
// Fallback kernels + generic scan (only used if bucket limits are exceeded).
// ---------------------------------------------------------------------------
__global__ void gat_deg(const int* __restrict__ src, int* __restrict__ deg, int E)
{
    int i = blockIdx.x * blockDim.x + threadIdx.x;
    if (i < E) atomicAdd(&deg[src[i]], 1);
}

__global__ void gat_scanA(const int* __restrict__ in, int* __restrict__ bsums, int n)
{
    __shared__ int s[256];
    int t = threadIdx.x;
    int i = blockIdx.x * 256 + t;
    s[t] = (i < n) ? in[i] : 0;
    __syncthreads();
    for (int off = 128; off > 0; off >>= 1) {
        if (t < off) s[t] += s[t + off];
        __syncthreads();
    }
    if (t == 0) bsums[blockIdx.x] = s[0];
}

__global__ void gat_scanB(const int* __restrict__ bsums, int* __restrict__ bofs, int nb)
{
    __shared__ int s[512];
    int t = threadIdx.x;
    int v = (t < nb) ? bsums[t] : 0;
    s[t] = v;
    __syncthreads();
    for (int off = 1; off < 512; off <<= 1) {
        int u = (t >= off) ? s[t - off] : 0;
        __syncthreads();
        s[t] += u;
        __syncthreads();
    }
    if (t < nb) bofs[t] = s[t] - v;
}

__global__ void gat_scanC(const int* __restrict__ in, const int* __restrict__ bofs,
                          int* __restrict__ out, int* __restrict__ cursor, int n)
{
    __shared__ int s[256];
    int t = threadIdx.x;
    int i = blockIdx.x * 256 + t;
    int v = (i < n) ? in[i] : 0;
    s[t] = v;
    __syncthreads();
    for (int off = 1; off < 256; off <<= 1) {
        int u = (t >= off) ? s[t - off] : 0;
        __syncthreads();
        s[t] += u;
        __syncthreads();
    }
    if (i < n) {
        int excl = bofs[blockIdx.x] + s[t] - v;
        out[i] = excl;
        if (cursor) cursor[i] = excl;
        if (i == n - 1) out[n] = excl + v;
    }
}

__global__ void gat_scatter(const int* __restrict__ src, const int* __restrict__ dst,
                            const float* __restrict__ adj,
                            const float* __restrict__ f1, const float* __restrict__ f2,
                            int* __restrict__ cursor, int2* __restrict__ csr, int E)
{
    int i = blockIdx.x * blockDim.x + threadIdx.x;
    if (i >= E) return;
    int sv = src[i], dv = dst[i];
    float a = adj[i];
    float e = a * f1[sv] + a * f2[dv];
    e = (e > 0.f) ? e : ALPHA * e;
    float p = __expf(e);
    int pos = atomicAdd(&cursor[sv], 1);
    csr[pos] = make_int2(dv, __float_as_int(p));
}

// ---------------------------------------------------------------------------
// Per-node weighted gather over bf16 h. One wave per node; 4 edge slots x
// 16 feature quads. Unroll x4: four independent (bc, hv) pairs in flight per
// wave. LDS strip padding carries p=0/boff=0, so reading past cnt is safe.
// ---------------------------------------------------------------------------
__global__ __launch_bounds__(256) void gat_gather(
    const int* __restrict__ row_start, const int2* __restrict__ csr,
    const unsigned short* __restrict__ hb,
    const float* __restrict__ bias, float* __restrict__ out, int N)
{
    __shared__ float2 sh[4][64];
    const int lane = threadIdx.x & 63;
    const int wid  = threadIdx.x >> 6;
    const int node = blockIdx.x * 4 + wid;
    if (node >= N) return;

    const int cg = lane & 15;
    const int eg = lane >> 4;

    const int rs = row_start[node];
    const int re = row_start[node + 1];
    float* op = out + (long long)node * 64;
    const float4 bl4 = *(const float4*)&bias[cg * 4];

    if (re <= rs) {
        if (lane < 16) *(float4*)&op[cg * 4] = bl4;
        return;
    }

    const char* hbase = (const char*)hb + (size_t)cg * 8;

    float acc0 = 0.f, acc1 = 0.f, acc2 = 0.f, acc3 = 0.f, ssum = 0.f;
    for (int base = rs; base < re; base += 64) {
        int idx = base + lane;
        float p = 0.f;
        int boff = 0;
        if (idx < re) {
            int2 de = csr[idx];
            boff = de.x << 7;            // dst * 128 bytes (bf16 row)
            p = __int_as_float(de.y);
        }
        ssum += p;
        sh[wid][lane] = make_float2(p, __int_as_float(boff));  // padding: p=0
        __builtin_amdgcn_wave_barrier();
        __threadfence_block();
        int cnt = re - base; if (cnt > 64) cnt = 64;
        for (int j = 0; j < cnt; j += 16) {
            float2 bcA = sh[wid][j + eg];
            float2 bcB = sh[wid][j + 4 + eg];
            float2 bcC = sh[wid][j + 8 + eg];
            float2 bcD = sh[wid][j + 12 + eg];
            uint2 hvA = *(const uint2*)(hbase + __float_as_int(bcA.y));
            uint2 hvB = *(const uint2*)(hbase + __float_as_int(bcB.y));
            uint2 hvC = *(const uint2*)(hbase + __float_as_int(bcC.y));
            uint2 hvD = *(const uint2*)(hbase + __float_as_int(bcD.y));
            float pA = bcA.x, pB = bcB.x, pC = bcC.x, pD = bcD.x;
            acc0 = fmaf(pA, __uint_as_float(hvA.x << 16), acc0);
            acc1 = fmaf(pA, __uint_as_float(hvA.x & 0xFFFF0000u), acc1);
            acc2 = fmaf(pA, __uint_as_float(hvA.y << 16), acc2);
            acc3 = fmaf(pA, __uint_as_float(hvA.y & 0xFFFF0000u), acc3);
            acc0 = fmaf(pB, __uint_as_float(hvB.x << 16), acc0);
            acc1 = fmaf(pB, __uint_as_float(hvB.x & 0xFFFF0000u), acc1);
            acc2 = fmaf(pB, __uint_as_float(hvB.y << 16), acc2);
            acc3 = fmaf(pB, __uint_as_float(hvB.y & 0xFFFF0000u), acc3);
            acc0 = fmaf(pC, __uint_as_float(hvC.x << 16), acc0);
            acc1 = fmaf(pC, __uint_as_float(hvC.x & 0xFFFF0000u), acc1);
            acc2 = fmaf(pC, __uint_as_float(hvC.y << 16), acc2);
            acc3 = fmaf(pC, __uint_as_float(hvC.y & 0xFFFF0000u), acc3);
            acc0 = fmaf(pD, __uint_as_float(hvD.x << 16), acc0);
            acc1 = fmaf(pD, __uint_as_float(hvD.x & 0xFFFF0000u), acc1);
            acc2 = fmaf(pD, __uint_as_float(hvD.y << 16), acc2);
            acc3 = fmaf(pD, __uint_as_float(hvD.y & 0xFFFF0000u), acc3);
        }
        __builtin_amdgcn_wave_barrier();
        __threadfence_block();
    }
#pragma unroll
    for (int d = 32; d > 0; d >>= 1) ssum += __shfl_xor(ssum, d);
    acc0 += __shfl_xor(acc0, 16); acc0 += __shfl_xor(acc0, 32);
    acc1 += __shfl_xor(acc1, 16); acc1 += __shfl_xor(acc1, 32);
    acc2 += __shfl_xor(acc2, 16); acc2 += __shfl_xor(acc2, 32);
    acc3 += __shfl_xor(acc3, 16); acc3 += __shfl_xor(acc3, 32);

    if (lane < 16) {
        const float inv = 1.f / ssum;
        float4 o;
        o.x = fmaf(acc0, inv, bl4.x);
        o.y = fmaf(acc1, inv, bl4.y);
        o.z = fmaf(acc2, inv, bl4.z);
        o.w = fmaf(acc3, inv, bl4.w);
        *(float4*)&op[cg * 4] = o;
    }
}

// ---------------------------------------------------------------------------
extern "C" void kernel_launch(void* const* d_in, const int* in_sizes, int n_in,
                              void* d_out, int out_size, void* d_ws, size_t ws_size,
                              hipStream_t stream)
{
    const float* x    = (const float*)d_in[0];
    const int*   esrc = (const int*)d_in[1];
    const int*   edst = (const int*)d_in[2];
    const float* adj  = (const float*)d_in[3];
    const float* W    = (const float*)d_in[4];
    const float* a1   = (const float*)d_in[5];
    const float* a1b  = (const float*)d_in[6];
    const float* a2   = (const float*)d_in[7];
    const float* a2b  = (const float*)d_in[8];
    const float* bias = (const float*)d_in[9];
    float* out = (float*)d_out;

    const int N = in_sizes[0] / 256;
    const int E = in_sizes[1];

    const int nbuck   = (N + 255) >> BUCKET_SHIFT;
    const int nhblk   = (E + HIST_CHUNK - 1) / HIST_CHUNK;
    const int nbinblk = (E + BW_CHUNK - 1) / BW_CHUNK;

    // workspace carve-up
    char* p = (char*)d_ws;
    unsigned short* hbuf = (unsigned short*)p;  p += (size_t)N * 64 * 2;
    p = (char*)(((uintptr_t)p + 255) & ~(uintptr_t)255);
    float* f1  = (float*)p;  p += (size_t)N * 4;
    float* f2  = (float*)p;  p += (size_t)N * 4;
    int* deg   = (int*)p;    p += (size_t)N * 4;
    int* row_start = (int*)p; p += (size_t)(N + 1) * 4;
    p = (char*)(((uintptr_t)p + 255) & ~(uintptr_t)255);
    int* cursor = (int*)p;   p += (size_t)N * 4;       // binned: nbuck entries used
    int* bsums  = (int*)p;   p += 512 * 4;
    int* bofs   = (int*)p;   p += 512 * 4;
    p = (char*)(((uintptr_t)p + 255) & ~(uintptr_t)255);
    int* bcnt  = (int*)p;    p += 512 * 4;
    int* bbase = (int*)p;    p += 520 * 4;
    p = (char*)(((uintptr_t)p + 255) & ~(uintptr_t)255);
    int2* csr  = (int2*)p;   p += (size_t)E * 8;
    const size_t required = (size_t)(p - (char*)d_ws);

    const bool binned = (nbuck <= 512) && (required <= ws_size);

    const int nbN = (N + 255) / 256;
    const int gemm_blocks = (N + GEMM_BM - 1) / GEMM_BM;

    if (binned) {
        hipMemsetAsync(bcnt, 0, 512 * 4, stream);
        hipLaunchKernelGGL(gat_hist, dim3(nhblk), dim3(512), 0, stream,
                           esrc, bcnt, E, nbuck);
        hipLaunchKernelGGL(gat_bscan, dim3(1), dim3(512), 0, stream,
                           bcnt, bbase, cursor, nbuck, E);
        hipLaunchKernelGGL(gat_gemm_binw, dim3(nbinblk + gemm_blocks), dim3(512), 0, stream,
                           x, W, a1, a1b, a2, a2b, hbuf, f1, f2, N,
                           esrc, edst, adj, cursor, csr, E, nbuck, nbinblk);
        hipLaunchKernelGGL(gat_bucket_scatter, dim3(nbuck), dim3(512), 0, stream,
                           bbase, row_start, f1, f2, csr, N, E);
    } else {
        hipMemsetAsync(deg, 0, (size_t)N * 4, stream);
        hipLaunchKernelGGL(gat_gemm, dim3(gemm_blocks), dim3(512), 0, stream,
                           x, W, a1, a1b, a2, a2b, hbuf, f1, f2, N);
        hipLaunchKernelGGL(gat_deg, dim3((E + 255) / 256), dim3(256), 0, stream,
                           esrc, deg, E);
        hipLaunchKernelGGL(gat_scanA, dim3(nbN), dim3(256), 0, stream, deg, bsums, N);
        hipLaunchKernelGGL(gat_scanB, dim3(1), dim3(512), 0, stream, bsums, bofs, nbN);
        hipLaunchKernelGGL(gat_scanC, dim3(nbN), dim3(256), 0, stream,
                           deg, bofs, row_start, cursor, N);
        hipLaunchKernelGGL(gat_scatter, dim3((E + 255) / 256), dim3(256), 0, stream,
                           esrc, edst, adj, f1, f2, cursor, csr, E);
    }

    hipLaunchKernelGGL(gat_gather, dim3((N + 3) / 4), dim3(256), 0, stream,
                       row_start, csr, hbuf, bias, out, N);
}

// Round 15
// 167.445 us; speedup vs baseline: 1.4432x; 1.0014x over previous
//
#include <hip/hip_runtime.h>
#include <math.h>
#include <stdint.h>

#define ALPHA 0.2f
#define HIST_CHUNK 8192           // edges per hist block (16 x 512)
#define BW_CHUNK 5120             // edges per binwrite block (10 x 512) - LDS fit
#define BUCKET_SHIFT 8            // 256 nodes per bucket
#define PHC_CAP 12288             // bucket LDS capacity; mean ~8192, +45 sigma
#define SMEM_BYTES 49152          // union: gemm 48K | binwrite 40K buf + aux

typedef __attribute__((ext_vector_type(8))) short bf16x8;
typedef __attribute__((ext_vector_type(4))) float f32x4;
typedef __attribute__((ext_vector_type(8))) unsigned short u16x8;

// bf16 round-to-nearest-even
__device__ __forceinline__ unsigned short f2bf(float f)
{
    unsigned int u = __float_as_uint(f);
    unsigned int r = (u + 0x7FFFu + ((u >> 16) & 1u)) >> 16;
    return (unsigned short)r;
}

// ---------------------------------------------------------------------------
// GEMM body: h = x @ W -> hb (bf16), f1/f2 from fp32 accumulators.
// 512 threads = 8 waves; tile 128 rows x 64 cols; BK=64. smem: wt 32K + xs 16K.
// ---------------------------------------------------------------------------
#define GEMM_BM 128

__device__ __forceinline__ void gemm_body(
    char* smem,
    const float* __restrict__ x, const float* __restrict__ W,
    const float* __restrict__ a1, const float* __restrict__ a1b,
    const float* __restrict__ a2, const float* __restrict__ a2b,
    unsigned short* __restrict__ hb, float* __restrict__ f1, float* __restrict__ f2,
    int N, int bid)
{
    unsigned short* wt = (unsigned short*)smem;            // 32 KB: wt[col][k]
    unsigned short* xs = (unsigned short*)(smem + 32768);  // 16 KB: xs[row][kchunk]

    const int tid  = threadIdx.x;
    const int lane = tid & 63;
    const int w    = tid >> 6;
    const int cg   = lane & 15;
    const int g    = lane >> 4;
    const long long row0 = (long long)bid * GEMM_BM;

    // stage W transposed (once): col c = tid>>3, k0 = (tid&7)*32
    {
        const int c  = tid >> 3;
        const int k0 = (tid & 7) * 32;
        unsigned short tmp[32];
#pragma unroll
        for (int j = 0; j < 32; ++j)
            tmp[j] = f2bf(W[(k0 + j) * 64 + c]);
        const int xorv = (c & 7) << 4;
        char* wb = (char*)wt + c * 512;
#pragma unroll
        for (int q = 0; q < 4; ++q) {
            int kbyte = (k0 + q * 8) * 2;
            *(u16x8*)(wb + (kbyte ^ xorv)) = *(u16x8*)&tmp[q * 8];
        }
    }

    f32x4 acc[4];
#pragma unroll
    for (int ct = 0; ct < 4; ++ct) acc[ct] = (f32x4){0.f, 0.f, 0.f, 0.f};

    const int arow  = w * 16 + cg;
    const int axor  = (arow & 7) << 4;
    char* const abase = (char*)xs + arow * 128;

    for (int kc = 0; kc < 256; kc += 64) {
        __syncthreads();
        {
            const int r  = tid >> 2;
            const int ks = (tid & 3) * 16;
            long long gr = row0 + r;
            if (gr > (long long)N - 1) gr = (long long)N - 1;
            const float* xp = &x[gr * 256 + kc + ks];
            float4 v0 = *(const float4*)&xp[0];
            float4 v1 = *(const float4*)&xp[4];
            float4 v2 = *(const float4*)&xp[8];
            float4 v3 = *(const float4*)&xp[12];
            unsigned short tmp[16];
            tmp[0]=f2bf(v0.x); tmp[1]=f2bf(v0.y); tmp[2]=f2bf(v0.z); tmp[3]=f2bf(v0.w);
            tmp[4]=f2bf(v1.x); tmp[5]=f2bf(v1.y); tmp[6]=f2bf(v1.z); tmp[7]=f2bf(v1.w);
            tmp[8]=f2bf(v2.x); tmp[9]=f2bf(v2.y); tmp[10]=f2bf(v2.z); tmp[11]=f2bf(v2.w);
            tmp[12]=f2bf(v3.x); tmp[13]=f2bf(v3.y); tmp[14]=f2bf(v3.z); tmp[15]=f2bf(v3.w);
            const int xorv = (r & 7) << 4;
            char* xb = (char*)xs + r * 128;
            *(u16x8*)(xb + ((ks * 2) ^ xorv))      = *(u16x8*)&tmp[0];
            *(u16x8*)(xb + ((ks * 2 + 16) ^ xorv)) = *(u16x8*)&tmp[8];
        }
        __syncthreads();

#pragma unroll
        for (int s = 0; s < 2; ++s) {
            bf16x8 af = *(bf16x8*)(abase + (((s * 32 + g * 8) * 2) ^ axor));
#pragma unroll
            for (int ct = 0; ct < 4; ++ct) {
                const int col = ct * 16 + cg;
                const int kbyte = (kc + s * 32) * 2 + g * 16;
                bf16x8 bf_ = *(bf16x8*)((char*)wt + col * 512 + (kbyte ^ ((col & 7) << 4)));
                acc[ct] = __builtin_amdgcn_mfma_f32_16x16x32_bf16(af, bf_, acc[ct], 0, 0, 0);
            }
        }
    }

    float a1v[4], a2v[4];
#pragma unroll
    for (int ct = 0; ct < 4; ++ct) {
        a1v[ct] = a1[ct * 16 + cg];
        a2v[ct] = a2[ct * 16 + cg];
    }
    const float b1 = a1b[0], b2 = a2b[0];

#pragma unroll
    for (int r = 0; r < 4; ++r) {
        const long long row = row0 + w * 16 + g * 4 + r;
        const bool ok = (row < N);
        float p1 = 0.f, p2 = 0.f;
#pragma unroll
        for (int ct = 0; ct < 4; ++ct) {
            float hv = acc[ct][r];
            if (ok) hb[row * 64 + ct * 16 + cg] = f2bf(hv);
            p1 = fmaf(hv, a1v[ct], p1);
            p2 = fmaf(hv, a2v[ct], p2);
        }
#pragma unroll
        for (int d = 8; d > 0; d >>= 1) {
            p1 += __shfl_xor(p1, d);
            p2 += __shfl_xor(p2, d);
        }
        if (ok && cg == 0) {
            f1[row] = p1 + b1;
            f2[row] = p2 + b2;
        }
    }
}

// ---------------------------------------------------------------------------
// Binwrite body: LDS counting-sort block pass. hist -> wave-level scan (3
// barriers, not 18) -> global range reservation -> sort payloads into LDS ->
// run-contiguous global writes.
// ---------------------------------------------------------------------------
__device__ __forceinline__ void binwrite_body(
    char* smem,
    const int* __restrict__ src, const int* __restrict__ dst,
    const float* __restrict__ adj,
    int* __restrict__ cursor, int2* __restrict__ bin, int E, int nbuck, int bid)
{
    int2* buf  = (int2*)smem;                        // 40 KB
    int* hist  = (int*)(smem + BW_CHUNK * 8);        // 2 KB
    int* lbase = hist + 512;                         // 2 KB
    int* gbase = lbase + 512;                        // 2 KB
    int* wtot  = gbase + 512;                        // 32 B
    const int tid = threadIdx.x;
    hist[tid] = 0;
    __syncthreads();

    const long long base = (long long)bid * BW_CHUNK;
#pragma unroll 2
    for (int k = 0; k < BW_CHUNK / 512; ++k) {
        long long i = base + k * 512 + tid;
        if (i < E) atomicAdd(&hist[src[i] >> BUCKET_SHIFT], 1);
    }
    __syncthreads();

    // wave-level scan: per-wave shfl_up inclusive scan + wave-total combine
    const int cnt = hist[tid];
    int incl = cnt;
#pragma unroll
    for (int d = 1; d < 64; d <<= 1) {
        int u = __shfl_up(incl, d);
        if ((tid & 63) >= d) incl += u;
    }
    if ((tid & 63) == 63) wtot[tid >> 6] = incl;
    __syncthreads();
    if (tid == 0) {
        int s = 0;
#pragma unroll
        for (int w2 = 0; w2 < 8; ++w2) { int t = wtot[w2]; wtot[w2] = s; s += t; }
    }
    __syncthreads();
    const int excl = incl - cnt + wtot[tid >> 6];
    lbase[tid] = excl;
    if (tid < nbuck) gbase[tid] = cnt ? atomicAdd(&cursor[tid], cnt) : 0;
    hist[tid] = excl;                    // running local cursor
    __syncthreads();

#pragma unroll 2
    for (int k = 0; k < BW_CHUNK / 512; ++k) {
        long long i = base + k * 512 + tid;
        if (i < E) {
            int s = src[i], d = dst[i];
            float a = adj[i];
            int lp = atomicAdd(&hist[s >> BUCKET_SHIFT], 1);
            buf[lp] = make_int2((d << BUCKET_SHIFT) | (s & 255), __float_as_int(a));
        }
    }
    __syncthreads();

    const int wv = tid >> 6, ln = tid & 63;
    for (int r = wv; r < nbuck; r += 8) {
        const int lb = lbase[r];
        const int len = hist[r] - lb;
        const int gb = gbase[r];
        for (int j = ln; j < len; j += 64)
            bin[gb + j] = buf[lb + j];
    }
}

// ---------------------------------------------------------------------------
// FUSED kernel with Bresenham role interleave: adjacent blocks alternate
// binwrite/gemm roles so every CU co-schedules MFMA waves with latency waves.
// ---------------------------------------------------------------------------
__global__ __launch_bounds__(512) void gat_gemm_binw(
    const float* __restrict__ x, const float* __restrict__ W,
    const float* __restrict__ a1, const float* __restrict__ a1b,
    const float* __restrict__ a2, const float* __restrict__ a2b,
    unsigned short* __restrict__ hb, float* __restrict__ f1, float* __restrict__ f2,
    int N,
    const int* __restrict__ src, const int* __restrict__ dst,
    const float* __restrict__ adj,
    int* __restrict__ cursor, int2* __restrict__ bin, int E, int nbuck,
    int nbinblk, int ntotal)
{
    __shared__ __align__(16) char smem[SMEM_BYTES];
    const int i = blockIdx.x;
    const int a = (int)(((long long)i * nbinblk) / ntotal);
    const int b = (int)(((long long)(i + 1) * nbinblk) / ntotal);
    if (b > a)
        binwrite_body(smem, src, dst, adj, cursor, bin, E, nbuck, a);
    else
        gemm_body(smem, x, W, a1, a1b, a2, a2b, hb, f1, f2, N, i - a);
}

// standalone gemm (fallback path)
__global__ __launch_bounds__(512) void gat_gemm(
    const float* __restrict__ x, const float* __restrict__ W,
    const float* __restrict__ a1, const float* __restrict__ a1b,
    const float* __restrict__ a2, const float* __restrict__ a2b,
    unsigned short* __restrict__ hb, float* __restrict__ f1, float* __restrict__ f2,
    int N)
{
    __shared__ __align__(16) char smem[SMEM_BYTES];
    gemm_body(smem, x, W, a1, a1b, a2, a2b, hb, f1, f2, N, blockIdx.x);
}

// ---------------------------------------------------------------------------
// Phase A: per-block LDS bucket histogram -> ONE global atomicAdd per bucket.
// ---------------------------------------------------------------------------
__global__ __launch_bounds__(512) void gat_hist(
    const int* __restrict__ src, int* __restrict__ bcnt, int E, int nbuck)
{
    __shared__ int hist[512];
    const int tid = threadIdx.x;
    hist[tid] = 0;
    __syncthreads();
    const long long base = (long long)blockIdx.x * HIST_CHUNK;
#pragma unroll 4
    for (int k = 0; k < HIST_CHUNK / 512; ++k) {
        long long i = base + k * 512 + tid;
        if (i < E) atomicAdd(&hist[src[i] >> BUCKET_SHIFT], 1);
    }
    __syncthreads();
    if (tid < nbuck && hist[tid]) atomicAdd(&bcnt[tid], hist[tid]);
}

// ---------------------------------------------------------------------------
// Single-block exclusive scan of bucket totals -> bbase[0..nbuck], cursor[].
// ---------------------------------------------------------------------------
__global__ __launch_bounds__(512) void gat_bscan(
    const int* __restrict__ bcnt, int* __restrict__ bbase,
    int* __restrict__ cursor, int nbuck, int E)
{
    __shared__ int s[512];
    const int t = threadIdx.x;
    int v = (t < nbuck) ? bcnt[t] : 0;
    s[t] = v;
    __syncthreads();
    for (int off = 1; off < 512; off <<= 1) {
        int u = (t >= off) ? s[t - off] : 0;
        __syncthreads();
        s[t] += u;
        __syncthreads();
    }
    if (t < nbuck) {
        int ex = s[t] - v;
        bbase[t]  = ex;
        cursor[t] = ex;
    }
    if (t == 0) bbase[nbuck] = E;
}

// ---------------------------------------------------------------------------
// Phase C: one block per bucket. Preload f1 (bucket-local LDS); degree hist +
// scan writes row_start; in-place scatter computing e = a*f1[s] + a*f2[d],
// leaky, exp -> csr {dst, p}.
// ---------------------------------------------------------------------------
__global__ __launch_bounds__(512) void gat_bucket_scatter(
    const int* __restrict__ bbase, int* __restrict__ row_start,
    const float* __restrict__ f1, const float* __restrict__ f2,
    int2* __restrict__ csr, int N, int E)
{
    __shared__ int2 buf[PHC_CAP];
    __shared__ int hist[256];
    __shared__ int sc[256];
    __shared__ float f1s[256];
    const int tid = threadIdx.x;
    const int b = blockIdx.x;
    const int n0 = b << BUCKET_SHIFT;
    int n1 = n0 + 256; if (n1 > N) n1 = N;
    const int nn = n1 - n0;

    const int bstart = bbase[b];
    const int bend   = bbase[b + 1];
    int cntb = bend - bstart;
    if (cntb > PHC_CAP) cntb = PHC_CAP;

    if (tid < 256) {
        hist[tid] = 0;
        f1s[tid] = (tid < nn) ? f1[n0 + tid] : 0.f;
    }
    for (int i = tid; i < cntb; i += 512) buf[i] = csr[bstart + i];
    __syncthreads();

    for (int i = tid; i < cntb; i += 512)
        atomicAdd(&hist[buf[i].x & 255], 1);
    __syncthreads();

    int v = (tid < 256) ? hist[tid] : 0;
    if (tid < 256) sc[tid] = v;
    __syncthreads();
    for (int off = 1; off < 256; off <<= 1) {
        int u = (tid < 256 && tid >= off) ? sc[tid - off] : 0;
        __syncthreads();
        if (tid < 256) sc[tid] += u;
        __syncthreads();
    }
    if (tid < 256) {
        int ex = bstart + sc[tid] - v;
        hist[tid] = ex;
        if (tid < nn) row_start[n0 + tid] = ex;
    }
    if (b == gridDim.x - 1 && tid == 0) row_start[N] = E;
    __syncthreads();

    for (int i = tid; i < cntb; i += 512) {
        int2 ev = buf[i];
        int sl = ev.x & 255;
        int dv = ev.x >> BUCKET_SHIFT;
        float a = __int_as_float(ev.y);
        float e = a * f1s[sl] + a * f2[dv];
        e = (e > 0.f) ? e : ALPHA * e;
        float p = __expf(e);
        int pos = atomicAdd(&hist[sl], 1);
        csr[pos] = make_int2(dv, __float_as_int(p));
    }
}

// ---------------------------------------------------------------------------
// Fallback kernels + generic scan (only used if bucket limits are exceeded).
// ---------------------------------------------------------------------------
__global__ void gat_deg(const int* __restrict__ src, int* __restrict__ deg, int E)
{
    int i = blockIdx.x * blockDim.x + threadIdx.x;
    if (i < E) atomicAdd(&deg[src[i]], 1);
}

__global__ void gat_scanA(const int* __restrict__ in, int* __restrict__ bsums, int n)
{
    __shared__ int s[256];
    int t = threadIdx.x;
    int i = blockIdx.x * 256 + t;
    s[t] = (i < n) ? in[i] : 0;
    __syncthreads();
    for (int off = 128; off > 0; off >>= 1) {
        if (t < off) s[t] += s[t + off];
        __syncthreads();
    }
    if (t == 0) bsums[blockIdx.x] = s[0];
}

__global__ void gat_scanB(const int* __restrict__ bsums, int* __restrict__ bofs, int nb)
{
    __shared__ int s[512];
    int t = threadIdx.x;
    int v = (t < nb) ? bsums[t] : 0;
    s[t] = v;
    __syncthreads();
    for (int off = 1; off < 512; off <<= 1) {
        int u = (t >= off) ? s[t - off] : 0;
        __syncthreads();
        s[t] += u;
        __syncthreads();
    }
    if (t < nb) bofs[t] = s[t] - v;
}

__global__ void gat_scanC(const int* __restrict__ in, const int* __restrict__ bofs,
                          int* __restrict__ out, int* __restrict__ cursor, int n)
{
    __shared__ int s[256];
    int t = threadIdx.x;
    int i = blockIdx.x * 256 + t;
    int v = (i < n) ? in[i] : 0;
    s[t] = v;
    __syncthreads();
    for (int off = 1; off < 256; off <<= 1) {
        int u = (t >= off) ? s[t - off] : 0;
        __syncthreads();
        s[t] += u;
        __syncthreads();
    }
    if (i < n) {
        int excl = bofs[blockIdx.x] + s[t] - v;
        out[i] = excl;
        if (cursor) cursor[i] = excl;
        if (i == n - 1) out[n] = excl + v;
    }
}

__global__ void gat_scatter(const int* __restrict__ src, const int* __restrict__ dst,
                            const float* __restrict__ adj,
                            const float* __restrict__ f1, const float* __restrict__ f2,
                            int* __restrict__ cursor, int2* __restrict__ csr, int E)
{
    int i = blockIdx.x * blockDim.x + threadIdx.x;
    if (i >= E) return;
    int sv = src[i], dv = dst[i];
    float a = adj[i];
    float e = a * f1[sv] + a * f2[dv];
    e = (e > 0.f) ? e : ALPHA * e;
    float p = __expf(e);
    int pos = atomicAdd(&cursor[sv], 1);
    csr[pos] = make_int2(dv, __float_as_int(p));
}

// ---------------------------------------------------------------------------
// Per-node weighted gather over bf16 h. One wave per node; 4 edge slots x
// 16 feature quads. Unroll x4: four independent (bc, hv) pairs in flight per
// wave. LDS strip padding carries p=0/boff=0, so reading past cnt is safe.
// ---------------------------------------------------------------------------
__global__ __launch_bounds__(256) void gat_gather(
    const int* __restrict__ row_start, const int2* __restrict__ csr,
    const unsigned short* __restrict__ hb,
    const float* __restrict__ bias, float* __restrict__ out, int N)
{
    __shared__ float2 sh[4][64];
    const int lane = threadIdx.x & 63;
    const int wid  = threadIdx.x >> 6;
    const int node = blockIdx.x * 4 + wid;
    if (node >= N) return;

    const int cg = lane & 15;
    const int eg = lane >> 4;

    const int rs = row_start[node];
    const int re = row_start[node + 1];
    float* op = out + (long long)node * 64;
    const float4 bl4 = *(const float4*)&bias[cg * 4];

    if (re <= rs) {
        if (lane < 16) *(float4*)&op[cg * 4] = bl4;
        return;
    }

    const char* hbase = (const char*)hb + (size_t)cg * 8;

    float acc0 = 0.f, acc1 = 0.f, acc2 = 0.f, acc3 = 0.f, ssum = 0.f;
    for (int base = rs; base < re; base += 64) {
        int idx = base + lane;
        float p = 0.f;
        int boff = 0;
        if (idx < re) {
            int2 de = csr[idx];
            boff = de.x << 7;            // dst * 128 bytes (bf16 row)
            p = __int_as_float(de.y);
        }
        ssum += p;
        sh[wid][lane] = make_float2(p, __int_as_float(boff));  // padding: p=0
        __builtin_amdgcn_wave_barrier();
        __threadfence_block();
        int cnt = re - base; if (cnt > 64) cnt = 64;
        for (int j = 0; j < cnt; j += 16) {
            float2 bcA = sh[wid][j + eg];
            float2 bcB = sh[wid][j + 4 + eg];
            float2 bcC = sh[wid][j + 8 + eg];
            float2 bcD = sh[wid][j + 12 + eg];
            uint2 hvA = *(const uint2*)(hbase + __float_as_int(bcA.y));
            uint2 hvB = *(const uint2*)(hbase + __float_as_int(bcB.y));
            uint2 hvC = *(const uint2*)(hbase + __float_as_int(bcC.y));
            uint2 hvD = *(const uint2*)(hbase + __float_as_int(bcD.y));
            float pA = bcA.x, pB = bcB.x, pC = bcC.x, pD = bcD.x;
            acc0 = fmaf(pA, __uint_as_float(hvA.x << 16), acc0);
            acc1 = fmaf(pA, __uint_as_float(hvA.x & 0xFFFF0000u), acc1);
            acc2 = fmaf(pA, __uint_as_float(hvA.y << 16), acc2);
            acc3 = fmaf(pA, __uint_as_float(hvA.y & 0xFFFF0000u), acc3);
            acc0 = fmaf(pB, __uint_as_float(hvB.x << 16), acc0);
            acc1 = fmaf(pB, __uint_as_float(hvB.x & 0xFFFF0000u), acc1);
            acc2 = fmaf(pB, __uint_as_float(hvB.y << 16), acc2);
            acc3 = fmaf(pB, __uint_as_float(hvB.y & 0xFFFF0000u), acc3);
            acc0 = fmaf(pC, __uint_as_float(hvC.x << 16), acc0);
            acc1 = fmaf(pC, __uint_as_float(hvC.x & 0xFFFF0000u), acc1);
            acc2 = fmaf(pC, __uint_as_float(hvC.y << 16), acc2);
            acc3 = fmaf(pC, __uint_as_float(hvC.y & 0xFFFF0000u), acc3);
            acc0 = fmaf(pD, __uint_as_float(hvD.x << 16), acc0);
            acc1 = fmaf(pD, __uint_as_float(hvD.x & 0xFFFF0000u), acc1);
            acc2 = fmaf(pD, __uint_as_float(hvD.y << 16), acc2);
            acc3 = fmaf(pD, __uint_as_float(hvD.y & 0xFFFF0000u), acc3);
        }
        __builtin_amdgcn_wave_barrier();
        __threadfence_block();
    }
#pragma unroll
    for (int d = 32; d > 0; d >>= 1) ssum += __shfl_xor(ssum, d);
    acc0 += __shfl_xor(acc0, 16); acc0 += __shfl_xor(acc0, 32);
    acc1 += __shfl_xor(acc1, 16); acc1 += __shfl_xor(acc1, 32);
    acc2 += __shfl_xor(acc2, 16); acc2 += __shfl_xor(acc2, 32);
    acc3 += __shfl_xor(acc3, 16); acc3 += __shfl_xor(acc3, 32);

    if (lane < 16) {
        const float inv = 1.f / ssum;
        float4 o;
        o.x = fmaf(acc0, inv, bl4.x);
        o.y = fmaf(acc1, inv, bl4.y);
        o.z = fmaf(acc2, inv, bl4.z);
        o.w = fmaf(acc3, inv, bl4.w);
        *(float4*)&op[cg * 4] = o;
    }
}

// ---------------------------------------------------------------------------
extern "C" void kernel_launch(void* const* d_in, const int* in_sizes, int n_in,
                              void* d_out, int out_size, void* d_ws, size_t ws_size,
                              hipStream_t stream)
{
    const float* x    = (const float*)d_in[0];
    const int*   esrc = (const int*)d_in[1];
    const int*   edst = (const int*)d_in[2];
    const float* adj  = (const float*)d_in[3];
    const float* W    = (const float*)d_in[4];
    const float* a1   = (const float*)d_in[5];
    const float* a1b  = (const float*)d_in[6];
    const float* a2   = (const float*)d_in[7];
    const float* a2b  = (const float*)d_in[8];
    const float* bias = (const float*)d_in[9];
    float* out = (float*)d_out;

    const int N = in_sizes[0] / 256;
    const int E = in_sizes[1];

    const int nbuck   = (N + 255) >> BUCKET_SHIFT;
    const int nhblk   = (E + HIST_CHUNK - 1) / HIST_CHUNK;
    const int nbinblk = (E + BW_CHUNK - 1) / BW_CHUNK;

    // workspace carve-up
    char* p = (char*)d_ws;
    unsigned short* hbuf = (unsigned short*)p;  p += (size_t)N * 64 * 2;
    p = (char*)(((uintptr_t)p + 255) & ~(uintptr_t)255);
    float* f1  = (float*)p;  p += (size_t)N * 4;
    float* f2  = (float*)p;  p += (size_t)N * 4;
    int* deg   = (int*)p;    p += (size_t)N * 4;
    int* row_start = (int*)p; p += (size_t)(N + 1) * 4;
    p = (char*)(((uintptr_t)p + 255) & ~(uintptr_t)255);
    int* cursor = (int*)p;   p += (size_t)N * 4;       // binned: nbuck entries used
    int* bsums  = (int*)p;   p += 512 * 4;
    int* bofs   = (int*)p;   p += 512 * 4;
    p = (char*)(((uintptr_t)p + 255) & ~(uintptr_t)255);
    int* bcnt  = (int*)p;    p += 512 * 4;
    int* bbase = (int*)p;    p += 520 * 4;
    p = (char*)(((uintptr_t)p + 255) & ~(uintptr_t)255);
    int2* csr  = (int2*)p;   p += (size_t)E * 8;
    const size_t required = (size_t)(p - (char*)d_ws);

    const bool binned = (nbuck <= 512) && (required <= ws_size);

    const int nbN = (N + 255) / 256;
    const int gemm_blocks = (N + GEMM_BM - 1) / GEMM_BM;

    if (binned) {
        const int ntotal = nbinblk + gemm_blocks;
        hipMemsetAsync(bcnt, 0, 512 * 4, stream);
        hipLaunchKernelGGL(gat_hist, dim3(nhblk), dim3(512), 0, stream,
                           esrc, bcnt, E, nbuck);
        hipLaunchKernelGGL(gat_bscan, dim3(1), dim3(512), 0, stream,
                           bcnt, bbase, cursor, nbuck, E);
        hipLaunchKernelGGL(gat_gemm_binw, dim3(ntotal), dim3(512), 0, stream,
                           x, W, a1, a1b, a2, a2b, hbuf, f1, f2, N,
                           esrc, edst, adj, cursor, csr, E, nbuck, nbinblk, ntotal);
        hipLaunchKernelGGL(gat_bucket_scatter, dim3(nbuck), dim3(512), 0, stream,
                           bbase, row_start, f1, f2, csr, N, E);
    } else {
        hipMemsetAsync(deg, 0, (size_t)N * 4, stream);
        hipLaunchKernelGGL(gat_gemm, dim3(gemm_blocks), dim3(512), 0, stream,
                           x, W, a1, a1b, a2, a2b, hbuf, f1, f2, N);
        hipLaunchKernelGGL(gat_deg, dim3((E + 255) / 256), dim3(256), 0, stream,
                           esrc, deg, E);
        hipLaunchKernelGGL(gat_scanA, dim3(nbN), dim3(256), 0, stream, deg, bsums, N);
        hipLaunchKernelGGL(gat_scanB, dim3(1), dim3(512), 0, stream, bsums, bofs, nbN);
        hipLaunchKernelGGL(gat_scanC, dim3(nbN), dim3(256), 0, stream,
                           deg, bofs, row_start, cursor, N);
        hipLaunchKernelGGL(gat_scatter, dim3((E + 255) / 256), dim3(256), 0, stream,
                           esrc, edst, adj, f1, f2, cursor, csr, E);
    }

    hipLaunchKernelGGL(gat_gather, dim3((N + 3) / 4), dim3(256), 0, stream,
                       row_start, csr, hbuf, bias, out, N);
}